// Round 16
// baseline (1992.747 us; speedup 1.0000x reference)
//
#include <hip/hip_runtime.h>
#include <hip/hip_bf16.h>
#include <stdint.h>

#define B 8
#define S 1024
#define L 1025
#define D 512
#define H 8
#define HD 64
#define NL 6
#define FF 2048
#define MAXD 64
#define OUTLEN 8
#define NC 10

#define MP 8320   // 65 * 128, padded M

typedef __bf16 bf16;
typedef __bf16 bf16x8 __attribute__((ext_vector_type(8)));
typedef __bf16 bf16x4 __attribute__((ext_vector_type(4)));
typedef float f32x4 __attribute__((ext_vector_type(4)));

__device__ __forceinline__ float fexp2(float x) { return __builtin_amdgcn_exp2f(x); }

// barrier WITHOUT the vmcnt(0) drain
#define LGKM_BARRIER() asm volatile("s_waitcnt lgkmcnt(0)\ns_barrier" ::: "memory")

__device__ __forceinline__ void gld16(const void* g, void* l) {
    __builtin_amdgcn_global_load_lds(
        (const __attribute__((address_space(1))) unsigned int*)g,
        (__attribute__((address_space(3))) unsigned int*)l,
        16, 0, 0);
}

// GELU with A&S 7.1.26 erf (|err| <= 1.5e-7), no libm call
__device__ __forceinline__ float fast_gelu(float v) {
    float x = v * 0.70710678118654752f;
    float ax = fabsf(x);
    float t = 1.f / fmaf(0.3275911f, ax, 1.f);
    float poly = t * (0.254829592f + t * (-0.284496736f + t * (1.421413741f +
                 t * (-1.453152027f + t * 1.061405429f))));
    float e = fexp2(-ax * ax * 1.4426950408889634f);
    float erfv = 1.f - poly * e;
    erfv = copysignf(erfv, x);
    return 0.5f * v * (1.f + erfv);
}

// ---------------- f32 -> bf16 conversion (vectorized) ----------------
__global__ __launch_bounds__(256) void cvt_k(const float* __restrict__ in,
                                             bf16* __restrict__ out, int n4)
{
    int i = blockIdx.x * 256 + threadIdx.x;
    if (i >= n4) return;
    float4 v = reinterpret_cast<const float4*>(in)[i];
    bf16x4 o;
    o[0] = (bf16)v.x; o[1] = (bf16)v.y; o[2] = (bf16)v.z; o[3] = (bf16)v.w;
    reinterpret_cast<bf16x4*>(out)[i] = o;
}

// ---------------- embedding ----------------
__global__ void embed_k(const int* __restrict__ src, const float* __restrict__ emb,
                        const float* __restrict__ cls, float* __restrict__ x,
                        bf16* __restrict__ xb)
{
    long i = (long)blockIdx.x * blockDim.x + threadIdx.x;
    if (i >= (long)B * L * D) return;
    int d = (int)(i % D);
    long bl = i / D;
    int l = (int)(bl % L);
    int b = (int)(bl / L);
    float v = (l == 0) ? cls[d] : emb[(long)src[b * S + (l - 1)] * D + d];
    x[i] = v;
    xb[i] = (bf16)v;
}

// ---------------- MFMA bf16 GEMM, 3-stage pipeline w/ counted vmcnt ----------
// (qkv + FF1; 128-row tiles)
template<int ACT, int OBF, int BIAS, int RT>
__global__ __launch_bounds__(256) void mgemm(const bf16* __restrict__ A,
                                             const bf16* __restrict__ W,
                                             const float* __restrict__ bias,
                                             float* __restrict__ Cf,
                                             bf16* __restrict__ Cb,
                                             int N, int K, int LDA)
{
    __shared__ bf16 Asl[3][RT * 32];
    __shared__ bf16 Bsl[3][128 * 32];
    int tid = threadIdx.x;
    int m0 = blockIdx.y * RT;
    int n0 = blockIdx.x * 128;
    int lane = tid & 63;
    int w = tid >> 6;
    int wbase = tid & ~63;
    int kb = (lane >> 4) * 8;
    int rsel = lane & 15;
    constexpr int FJ = (RT == 128) ? 4 : 2;
    constexpr int CW = (RT == 128) ? 64 : 32;
    int wr, wc;
    if constexpr (RT == 128) { wr = w >> 1; wc = w & 1; }
    else                     { wr = 0;      wc = w;     }
    f32x4 acc[4][FJ] = {};

    auto stage = [&](int buf, int k0) {
        if constexpr (RT == 128) {
#pragma unroll
            for (int r = 0; r < 2; r++) {
                int s = r * 256 + tid;
                int sb = r * 256 + wbase;
                gld16(A + (size_t)(m0 + (s >> 2)) * LDA + k0 + (s & 3) * 8, &Asl[buf][(size_t)sb * 8]);
                gld16(W + (size_t)(n0 + (s >> 2)) * LDA + k0 + (s & 3) * 8, &Bsl[buf][(size_t)sb * 8]);
            }
        } else {
            gld16(A + (size_t)(m0 + (tid >> 2)) * LDA + k0 + (tid & 3) * 8, &Asl[buf][(size_t)wbase * 8]);
#pragma unroll
            for (int r = 0; r < 2; r++) {
                int s = r * 256 + tid;
                int sb = r * 256 + wbase;
                gld16(W + (size_t)(n0 + (s >> 2)) * LDA + k0 + (s & 3) * 8, &Bsl[buf][(size_t)sb * 8]);
            }
        }
    };

    stage(0, 0);
    if (32 < K) stage(1, 32);

    int cur = 0;
    for (int k0 = 0; k0 < K; k0 += 32) {
        if constexpr (RT == 128)
            asm volatile("s_waitcnt vmcnt(4)\ns_barrier" ::: "memory");
        else
            asm volatile("s_waitcnt vmcnt(3)\ns_barrier" ::: "memory");
        int b2 = cur + 2; if (b2 >= 3) b2 -= 3;
        if (k0 + 64 < K) stage(b2, k0 + 64);

        bf16x8 af[4], bfr[FJ];
#pragma unroll
        for (int fi = 0; fi < 4; fi++)
            af[fi] = *reinterpret_cast<const bf16x8*>(&Asl[cur][(wr * 64 + fi * 16 + rsel) * 32 + kb]);
#pragma unroll
        for (int fj = 0; fj < FJ; fj++)
            bfr[fj] = *reinterpret_cast<const bf16x8*>(&Bsl[cur][(wc * CW + fj * 16 + rsel) * 32 + kb]);
#pragma unroll
        for (int fi = 0; fi < 4; fi++)
#pragma unroll
            for (int fj = 0; fj < FJ; fj++)
                acc[fi][fj] = __builtin_amdgcn_mfma_f32_16x16x32_bf16(af[fi], bfr[fj], acc[fi][fj], 0, 0, 0);
        cur = (cur + 1 == 3) ? 0 : cur + 1;
    }
    int rowb = (lane >> 4) * 4;
    int colb = lane & 15;
#pragma unroll
    for (int fi = 0; fi < 4; fi++) {
#pragma unroll
        for (int fj = 0; fj < FJ; fj++) {
            int col = n0 + wc * CW + fj * 16 + colb;
            float bsv = BIAS ? bias[col] : 0.f;
#pragma unroll
            for (int i = 0; i < 4; i++) {
                int row = m0 + wr * 64 + fi * 16 + rowb + i;
                float v = acc[fi][fj][i] + bsv;
                if (ACT) v = fast_gelu(v);
                if (OBF) Cb[(size_t)row * N + col] = (bf16)v;
                else     Cf[(size_t)row * N + col] = v;
            }
        }
    }
}

// ---------------- fused GEMM + residual + LayerNorm (N = 512 fixed) ----------
// Block: 16 rows x 512 cols, grid MP/16 = 520. 4 waves, wave w owns cols
// w*128..+127 of all 16 rows -> block owns COMPLETE rows, LN done in-kernel:
// outF/outB = LayerNorm(xres + A@W^T + bias) * gam + bet.
__global__ __launch_bounds__(256) void gemm_ln(const bf16* __restrict__ A,
                                               const bf16* __restrict__ W,
                                               const float* __restrict__ bias,
                                               const float* __restrict__ xres,
                                               const float* __restrict__ gam,
                                               const float* __restrict__ bet,
                                               float* __restrict__ outF,
                                               bf16* __restrict__ outB,
                                               int K)
{
    __shared__ bf16 Asl[2][16 * 32];
    __shared__ bf16 Bsl[2][512 * 32];
    __shared__ float red[2][4][16];
    int tid = threadIdx.x;
    int m0 = blockIdx.x * 16;
    int lane = tid & 63;
    int w = tid >> 6;
    int wbase = tid & ~63;
    int ln15 = lane & 15, g4 = lane >> 4;
    int kb = g4 * 8;
    f32x4 acc[8] = {};

    auto stage = [&](int buf, int k0) {
        if (w == 0)
            gld16(A + (size_t)(m0 + (tid >> 2)) * K + k0 + (tid & 3) * 8, &Asl[buf][0]);
#pragma unroll
        for (int r = 0; r < 8; r++) {
            int s = r * 256 + tid;
            gld16(W + (size_t)(s >> 2) * K + k0 + (s & 3) * 8,
                  &Bsl[buf][(size_t)(r * 256 + wbase) * 8]);
        }
    };

    stage(0, 0);
    __syncthreads();

    for (int k0 = 0; k0 < K; k0 += 32) {
        int cur = (k0 >> 5) & 1;
        if (k0 + 32 < K) stage(cur ^ 1, k0 + 32);
        bf16x8 af = *reinterpret_cast<const bf16x8*>(&Asl[cur][ln15 * 32 + kb]);
        bf16x8 bfr[8];
#pragma unroll
        for (int fj = 0; fj < 8; fj++)
            bfr[fj] = *reinterpret_cast<const bf16x8*>(&Bsl[cur][(w * 128 + fj * 16 + ln15) * 32 + kb]);
#pragma unroll
        for (int fj = 0; fj < 8; fj++)
            acc[fj] = __builtin_amdgcn_mfma_f32_16x16x32_bf16(af, bfr[fj], acc[fj], 0, 0, 0);
        __syncthreads();
    }

    // epilogue: v = acc + bias + xres, then row-LN across the block's 512 cols
    int col[8];
    float bcol[8], gcol[8], betcol[8];
#pragma unroll
    for (int fj = 0; fj < 8; fj++) {
        col[fj] = w * 128 + fj * 16 + ln15;
        bcol[fj] = bias[col[fj]];
        gcol[fj] = gam[col[fj]];
        betcol[fj] = bet[col[fj]];
    }
    f32x4 v[8];
#pragma unroll
    for (int fj = 0; fj < 8; fj++) {
#pragma unroll
        for (int i = 0; i < 4; i++) {
            int row = m0 + g4 * 4 + i;
            v[fj][i] = acc[fj][i] + bcol[fj] + xres[(size_t)row * 512 + col[fj]];
        }
    }
    f32x4 psum = {}, psq = {};
#pragma unroll
    for (int fj = 0; fj < 8; fj++) {
        psum += v[fj];
        psq += v[fj] * v[fj];
    }
#pragma unroll
    for (int off = 1; off < 16; off <<= 1) {
#pragma unroll
        for (int i = 0; i < 4; i++) {
            psum[i] += __shfl_xor(psum[i], off, 16);
            psq[i] += __shfl_xor(psq[i], off, 16);
        }
    }
    if (ln15 == 0) {
#pragma unroll
        for (int i = 0; i < 4; i++) {
            red[0][w][g4 * 4 + i] = psum[i];
            red[1][w][g4 * 4 + i] = psq[i];
        }
    }
    __syncthreads();
    float mean[4], rs[4];
#pragma unroll
    for (int i = 0; i < 4; i++) {
        int r16 = g4 * 4 + i;
        float s = red[0][0][r16] + red[0][1][r16] + red[0][2][r16] + red[0][3][r16];
        float sq = red[1][0][r16] + red[1][1][r16] + red[1][2][r16] + red[1][3][r16];
        mean[i] = s * (1.f / 512.f);
        float var = sq * (1.f / 512.f) - mean[i] * mean[i];
        rs[i] = rsqrtf(var + 1e-5f);
    }
#pragma unroll
    for (int fj = 0; fj < 8; fj++) {
#pragma unroll
        for (int i = 0; i < 4; i++) {
            int row = m0 + g4 * 4 + i;
            float o = (v[fj][i] - mean[i]) * rs[i] * gcol[fj] + betcol[fj];
            outF[(size_t)row * 512 + col[fj]] = o;
            outB[(size_t)row * 512 + col[fj]] = (bf16)o;
        }
    }
}

// ---------------- MFMA flash attention v7: 2 q-tiles share K/V pipeline -------
__global__ __launch_bounds__(256) void fattn_k(const bf16* __restrict__ qkv,
                                               const float* __restrict__ rel_emb_l,
                                               const unsigned char* __restrict__ pad,
                                               bf16* __restrict__ ob)
{
    constexpr int PIT = 72;
    __shared__ bf16 Vt[2][64 * PIT];       // V^T[d][k ^ ((d>>3)<<3)]
    __shared__ bf16 Psh[4][2][16 * PIT];   // per-wave, per-qq P[q][kv]
    __shared__ float bias2s[2 * MAXD + 1];
    __shared__ float colm[2][64];

    const int bh = blockIdx.x;
    const int qt = blockIdx.y;
    const int h = bh & 7, b = bh >> 3;
    const int q0 = qt * 128;
    const int tid = threadIdx.x;
    const int lane = tid & 63;
    const int w = tid >> 6;
    const int ln15 = lane & 15, g4 = lane >> 4;
    const int kb8 = g4 * 8;
    constexpr float LOG2E = 1.4426950408889634f;
    constexpr float C2 = 0.125f * LOG2E;

    const char* base = (const char*)qkv + (size_t)(b * L) * 3072 + (size_t)h * (HD * 2);

    for (int i = tid; i < 2 * MAXD + 1; i += 256) bias2s[i] = rel_emb_l[i * H + h] * LOG2E;
    if (tid < 64) colm[0][tid] = (tid > 0 && pad[(size_t)b * S + tid - 1]) ? -1e9f : 0.f;

    int qrow[2];
    bf16x8 qa[2][2];
#pragma unroll
    for (int qq = 0; qq < 2; qq++) {
        qrow[qq] = q0 + qq * 64 + w * 16 + ln15;
        qa[qq][0] = *(const bf16x8*)(base + (size_t)qrow[qq] * 3072 + g4 * 16);
        qa[qq][1] = *(const bf16x8*)(base + (size_t)qrow[qq] * 3072 + 64 + g4 * 16);
    }

    const int vr = tid >> 3;
    const int vd0 = (tid & 7) * 8;
    const int vsw = ((vd0 >> 3) & 7) << 3;

    { // prologue: stage V tile 0
        bf16x8 a = *(const bf16x8*)(base + (size_t)vr * 3072 + 2048 + vd0 * 2);
        bf16x8 c = *(const bf16x8*)(base + (size_t)(vr + 32) * 3072 + 2048 + vd0 * 2);
#pragma unroll
        for (int j = 0; j < 8; j++) {
            Vt[0][(vd0 + j) * PIT + (vr ^ vsw)] = a[j];
            Vt[0][(vd0 + j) * PIT + ((vr + 32) ^ vsw)] = c[j];
        }
    }
    bf16x8 kr[4][2];
#pragma unroll
    for (int fj = 0; fj < 4; fj++) {
        const char* rp = base + (size_t)(fj * 16 + ln15) * 3072 + 1024 + g4 * 16;
        kr[fj][0] = *(const bf16x8*)(rp);
        kr[fj][1] = *(const bf16x8*)(rp + 64);
    }
    LGKM_BARRIER();

    f32x4 oacc[2][4] = {};
    float m_prev[2] = {-1e30f, -1e30f};
    float l_sum[2] = {0.f, 0.f};

    for (int t = 0; t < 17; t++) {
        const int k0 = t * 64;
        const int k0n = (k0 + 64 > 1024) ? 1024 : (k0 + 64);
        const int cur = t & 1;

        bf16x8 vA = *(const bf16x8*)(base + (size_t)(k0n + vr) * 3072 + 2048 + vd0 * 2);
        bf16x8 vB = *(const bf16x8*)(base + (size_t)(k0n + vr + 32) * 3072 + 2048 + vd0 * 2);

        f32x4 sacc[2][4] = {};
#pragma unroll
        for (int qq = 0; qq < 2; qq++)
#pragma unroll
            for (int fj = 0; fj < 4; fj++) {
                sacc[qq][fj] = __builtin_amdgcn_mfma_f32_16x16x32_bf16(kr[fj][0], qa[qq][0], sacc[qq][fj], 0, 0, 0);
                sacc[qq][fj] = __builtin_amdgcn_mfma_f32_16x16x32_bf16(kr[fj][1], qa[qq][1], sacc[qq][fj], 0, 0, 0);
            }
#pragma unroll
        for (int fj = 0; fj < 4; fj++) {
            const char* rp = base + (size_t)(k0n + fj * 16 + ln15) * 3072 + 1024 + g4 * 16;
            kr[fj][0] = *(const bf16x8*)(rp);
            kr[fj][1] = *(const bf16x8*)(rp + 64);
        }

        f32x4 cm[4];
#pragma unroll
        for (int fj = 0; fj < 4; fj++)
            cm[fj] = *(const f32x4*)&colm[cur][fj * 16 + g4 * 4];

#pragma unroll
        for (int qq = 0; qq < 2; qq++) {
            float sv[4][4];
            const int relbw = k0 - q0 - qq * 64 - w * 16;
            if (relbw >= MAXD + 15 || relbw <= -MAXD - 63) {
                const float bu = bias2s[relbw > 0 ? 2 * MAXD : 0];
#pragma unroll
                for (int fj = 0; fj < 4; fj++)
#pragma unroll
                    for (int i = 0; i < 4; i++)
                        sv[fj][i] = fmaf(sacc[qq][fj][i], C2, bu + cm[fj][i]);
            } else {
                const int relb = k0 - qrow[qq];
#pragma unroll
                for (int fj = 0; fj < 4; fj++)
#pragma unroll
                    for (int i = 0; i < 4; i++) {
                        int rel = relb + fj * 16 + g4 * 4 + i;
                        rel = rel < -MAXD ? -MAXD : (rel > MAXD ? MAXD : rel);
                        sv[fj][i] = fmaf(sacc[qq][fj][i], C2, bias2s[rel + MAXD] + cm[fj][i]);
                    }
            }

            float mx = sv[0][0];
#pragma unroll
            for (int fj = 0; fj < 4; fj++)
#pragma unroll
                for (int i = 0; i < 4; i++) mx = fmaxf(mx, sv[fj][i]);
            mx = fmaxf(mx, __shfl_xor(mx, 16));
            mx = fmaxf(mx, __shfl_xor(mx, 32));
            const float mnew = fmaxf(m_prev[qq], mx);
            const float corr = fexp2(m_prev[qq] - mnew);
            float rsum = 0.f;
            float pb[4][4];
#pragma unroll
            for (int fj = 0; fj < 4; fj++)
#pragma unroll
                for (int i = 0; i < 4; i++) {
                    float p = fexp2(sv[fj][i] - mnew);
                    pb[fj][i] = p;
                    rsum += p;
                }
            rsum += __shfl_xor(rsum, 16);
            rsum += __shfl_xor(rsum, 32);
            l_sum[qq] = l_sum[qq] * corr + rsum;
            m_prev[qq] = mnew;
#pragma unroll
            for (int fd = 0; fd < 4; fd++) oacc[qq][fd] *= corr;

#pragma unroll
            for (int fj = 0; fj < 4; fj++) {
                union { bf16 hh[4]; unsigned long long u; } pk;
                pk.hh[0] = (bf16)pb[fj][0]; pk.hh[1] = (bf16)pb[fj][1];
                pk.hh[2] = (bf16)pb[fj][2]; pk.hh[3] = (bf16)pb[fj][3];
                *(unsigned long long*)&Psh[w][qq][ln15 * PIT + fj * 16 + g4 * 4] = pk.u;
            }
        }

#pragma unroll
        for (int j = 0; j < 8; j++) {
            Vt[cur ^ 1][(vd0 + j) * PIT + (vr ^ vsw)] = vA[j];
            Vt[cur ^ 1][(vd0 + j) * PIT + ((vr + 32) ^ vsw)] = vB[j];
        }
        if (tid < 64) {
            int gk = k0 + 64 + tid;
            int pi = (gk <= 1024) ? gk - 1 : 0;
            colm[cur ^ 1][tid] = (gk > 1024 || pad[(size_t)b * S + pi]) ? -1e9f : 0.f;
        }

        LGKM_BARRIER();   // D1

        bf16x8 pa[2][2];
#pragma unroll
        for (int qq = 0; qq < 2; qq++) {
            pa[qq][0] = *(const bf16x8*)&Psh[w][qq][ln15 * PIT + kb8];
            pa[qq][1] = *(const bf16x8*)&Psh[w][qq][ln15 * PIT + 32 + kb8];
        }
#pragma unroll
        for (int fd = 0; fd < 4; fd++) {
            const int d = fd * 16 + ln15;
            const int vx = ((d >> 3) & 7) << 3;
            bf16x8 af0 = *(const bf16x8*)&Vt[cur][d * PIT + (kb8 ^ vx)];
            bf16x8 af1 = *(const bf16x8*)&Vt[cur][d * PIT + ((32 + kb8) ^ vx)];
            oacc[0][fd] = __builtin_amdgcn_mfma_f32_16x16x32_bf16(af0, pa[0][0], oacc[0][fd], 0, 0, 0);
            oacc[0][fd] = __builtin_amdgcn_mfma_f32_16x16x32_bf16(af1, pa[0][1], oacc[0][fd], 0, 0, 0);
            oacc[1][fd] = __builtin_amdgcn_mfma_f32_16x16x32_bf16(af0, pa[1][0], oacc[1][fd], 0, 0, 0);
            oacc[1][fd] = __builtin_amdgcn_mfma_f32_16x16x32_bf16(af1, pa[1][1], oacc[1][fd], 0, 0, 0);
        }
        LGKM_BARRIER();   // D2
    }

#pragma unroll
    for (int qq = 0; qq < 2; qq++) {
        if (qrow[qq] < L) {
            const float inv = 1.f / l_sum[qq];
            bf16* op = ob + (size_t)(b * L + qrow[qq]) * D + h * HD + g4 * 4;
#pragma unroll
            for (int fd = 0; fd < 4; fd++) {
                bf16x4 r;
#pragma unroll
                for (int i = 0; i < 4; i++) r[i] = (bf16)(oacc[qq][fd][i] * inv);
                *(bf16x4*)(op + fd * 16) = r;
            }
        }
    }
}

// ---------------- final LN (row 0 only) + classifier ----------------
__global__ __launch_bounds__(256) void cls_k(const float* __restrict__ x,
                                             const float* __restrict__ ng,
                                             const float* __restrict__ nb,
                                             const float* __restrict__ cw,
                                             const float* __restrict__ cb,
                                             float* __restrict__ out)
{
    int b = blockIdx.x;
    __shared__ float xn[D];
    __shared__ float red[8];
    int tid = threadIdx.x;
    const float* xp = x + (size_t)(b * L) * D;
    float v0 = xp[tid], v1 = xp[tid + 256];
    float s = v0 + v1;
    for (int off = 32; off; off >>= 1) s += __shfl_down(s, off, 64);
    int lane = tid & 63, wid = tid >> 6;
    if (lane == 0) red[wid] = s;
    __syncthreads();
    if (tid == 0) red[0] = red[0] + red[1] + red[2] + red[3];
    __syncthreads();
    float mean = red[0] * (1.f / D);
    float d0 = v0 - mean, d1 = v1 - mean;
    float sq = d0 * d0 + d1 * d1;
    for (int off = 32; off; off >>= 1) sq += __shfl_down(sq, off, 64);
    if (lane == 0) red[4 + wid] = sq;
    __syncthreads();
    if (tid == 0) red[4] = red[4] + red[5] + red[6] + red[7];
    __syncthreads();
    float rs = rsqrtf(red[4] * (1.f / D) + 1e-5f);
    xn[tid] = d0 * rs * ng[tid] + nb[tid];
    xn[tid + 256] = d1 * rs * ng[tid + 256] + nb[tid + 256];
    __syncthreads();
    for (int o = tid; o < OUTLEN * NC; o += 256) {
        float acc = cb[o];
        const float* wp = cw + (size_t)o * D;
        for (int d = 0; d < D; d++) acc += xn[d] * wp[d];
        out[b * OUTLEN * NC + o] = acc;
    }
}

extern "C" void kernel_launch(void* const* d_in, const int* in_sizes, int n_in,
                              void* d_out, int out_size, void* d_ws, size_t ws_size,
                              hipStream_t stream) {
    const int* src = (const int*)d_in[0];
    const unsigned char* pad = (const unsigned char*)d_in[1];
    const float* emb = (const float*)d_in[2];
    const float* cls_token = (const float*)d_in[3];
    const float* qkv_w = (const float*)d_in[4];
    const float* qkv_b = (const float*)d_in[5];
    const float* out_w = (const float*)d_in[6];
    const float* out_b = (const float*)d_in[7];
    const float* rel_emb = (const float*)d_in[8];
    const float* ln1_g = (const float*)d_in[9];
    const float* ln1_b = (const float*)d_in[10];
    const float* w1 = (const float*)d_in[11];
    const float* b1 = (const float*)d_in[12];
    const float* w2 = (const float*)d_in[13];
    const float* b2 = (const float*)d_in[14];
    const float* ln2_g = (const float*)d_in[15];
    const float* ln2_b = (const float*)d_in[16];
    const float* norm_g = (const float*)d_in[17];
    const float* norm_b = (const float*)d_in[18];
    const float* cls_w = (const float*)d_in[19];
    const float* cls_b = (const float*)d_in[20];
    float* out = (float*)d_out;

    char* ws = (char*)d_ws;
    size_t off = 0;
    float* x   = (float*)(ws + off); off += (size_t)MP * D * 4;
    bf16*  xb  = (bf16*) (ws + off); off += (size_t)MP * D * 2;
    float* x2  = (float*)(ws + off); off += (size_t)MP * D * 4;
    bf16*  x2b = (bf16*) (ws + off); off += (size_t)MP * D * 2;
    char*  R   = ws + off;           off += (size_t)MP * 3 * D * 4; // qkvb | hb
    bf16*  qkvb = (bf16*)R;                              // MP*3D*2
    bf16*  hb  = (bf16*)R;                               // MP*FF*2 (after attn)
    bf16*  obf = (bf16*) (ws + off); off += (size_t)MP * D * 2;

    const size_t WQ = (size_t)NL * 3 * D * D;
    const size_t WO = (size_t)NL * D * D;
    const size_t W1E = (size_t)NL * FF * D;
    const size_t W2E = (size_t)NL * D * FF;
    const size_t WALL = WQ + WO + W1E + W2E;
    bool all_w = (off + WALL * 2) <= ws_size;

    bf16 *wq_a = nullptr, *wo_a = nullptr, *w1_a = nullptr, *w2_a = nullptr, *wbuf = nullptr;
    if (all_w) {
        wq_a = (bf16*)(ws + off);
        wo_a = wq_a + WQ;
        w1_a = wo_a + WO;
        w2_a = w1_a + W1E;
        int n4;
        n4 = (int)(WQ / 4);  cvt_k<<<dim3((n4 + 255) / 256), 256, 0, stream>>>(qkv_w, wq_a, n4);
        n4 = (int)(WO / 4);  cvt_k<<<dim3((n4 + 255) / 256), 256, 0, stream>>>(out_w, wo_a, n4);
        n4 = (int)(W1E / 4); cvt_k<<<dim3((n4 + 255) / 256), 256, 0, stream>>>(w1, w1_a, n4);
        n4 = (int)(W2E / 4); cvt_k<<<dim3((n4 + 255) / 256), 256, 0, stream>>>(w2, w2_a, n4);
    } else {
        wbuf = (bf16*)(ws + off); // per-layer rotating buffer
    }

    {
        long total = (long)B * L * D;
        embed_k<<<dim3((unsigned)((total + 255) / 256)), 256, 0, stream>>>(src, emb, cls_token, x, xb);
    }
    for (int l = 0; l < NL; l++) {
        const float* qb  = qkv_b + (size_t)l * 3 * D;
        const float* obi = out_b + (size_t)l * D;
        const float* re  = rel_emb + (size_t)l * (2 * MAXD + 1) * H;
        const float* g1  = ln1_g + (size_t)l * D;
        const float* be1 = ln1_b + (size_t)l * D;
        const float* B1p = b1 + (size_t)l * FF;
        const float* B2p = b2 + (size_t)l * D;
        const float* g2  = ln2_g + (size_t)l * D;
        const float* be2 = ln2_b + (size_t)l * D;

        const bf16 *wqb, *wob, *w1b, *w2b;
        if (all_w) {
            wqb = wq_a + (size_t)l * 3 * D * D;
            wob = wo_a + (size_t)l * D * D;
            w1b = w1_a + (size_t)l * FF * D;
            w2b = w2_a + (size_t)l * D * FF;
        } else {
            bf16* wp_ = wbuf;
            wqb = wp_;            wp_ += 3 * D * D;
            wob = wp_;            wp_ += D * D;
            w1b = wp_;            wp_ += FF * D;
            w2b = wp_;
            int n4;
            n4 = 3 * D * D / 4; cvt_k<<<dim3((n4 + 255) / 256), 256, 0, stream>>>(qkv_w + (size_t)l * 3 * D * D, (bf16*)wqb, n4);
            n4 = D * D / 4;     cvt_k<<<dim3((n4 + 255) / 256), 256, 0, stream>>>(out_w + (size_t)l * D * D, (bf16*)wob, n4);
            n4 = FF * D / 4;    cvt_k<<<dim3((n4 + 255) / 256), 256, 0, stream>>>(w1 + (size_t)l * FF * D, (bf16*)w1b, n4);
            n4 = D * FF / 4;    cvt_k<<<dim3((n4 + 255) / 256), 256, 0, stream>>>(w2 + (size_t)l * D * FF, (bf16*)w2b, n4);
        }

        mgemm<0, 1, 1, 128><<<dim3(3 * D / 128, MP / 128), 256, 0, stream>>>(xb, wqb, qb, nullptr, qkvb, 3 * D, D, D);
        fattn_k<<<dim3(B * H, 9), 256, 0, stream>>>(qkvb, re, pad, obf);
        gemm_ln<<<dim3(MP / 16), 256, 0, stream>>>(obf, wob, obi, x, g1, be1, x2, x2b, D);
        mgemm<1, 1, 1, 128><<<dim3(FF / 128, MP / 128), 256, 0, stream>>>(x2b, w1b, B1p, nullptr, hb, FF, D, D);
        gemm_ln<<<dim3(MP / 16), 256, 0, stream>>>(hb, w2b, B2p, x2, g2, be2, x, xb, FF);
    }
    cls_k<<<dim3(B), 256, 0, stream>>>(x, norm_g, norm_b, cls_w, cls_b, out);
}

// Round 17
// 1474.941 us; speedup vs baseline: 1.3511x; 1.3511x over previous
//
#include <hip/hip_runtime.h>
#include <hip/hip_bf16.h>
#include <stdint.h>

#define B 8
#define S 1024
#define L 1025
#define D 512
#define H 8
#define HD 64
#define NL 6
#define FF 2048
#define MAXD 64
#define OUTLEN 8
#define NC 10

#define MP 8320   // 65 * 128, padded M

typedef __bf16 bf16;
typedef __bf16 bf16x8 __attribute__((ext_vector_type(8)));
typedef __bf16 bf16x4 __attribute__((ext_vector_type(4)));
typedef float f32x4 __attribute__((ext_vector_type(4)));

__device__ __forceinline__ float fexp2(float x) { return __builtin_amdgcn_exp2f(x); }

// barrier WITHOUT the vmcnt(0) drain
#define LGKM_BARRIER() asm volatile("s_waitcnt lgkmcnt(0)\ns_barrier" ::: "memory")

__device__ __forceinline__ void gld16(const void* g, void* l) {
    __builtin_amdgcn_global_load_lds(
        (const __attribute__((address_space(1))) unsigned int*)g,
        (__attribute__((address_space(3))) unsigned int*)l,
        16, 0, 0);
}

// GELU with A&S 7.1.26 erf (|err| <= 1.5e-7), no libm call
__device__ __forceinline__ float fast_gelu(float v) {
    float x = v * 0.70710678118654752f;
    float ax = fabsf(x);
    float t = 1.f / fmaf(0.3275911f, ax, 1.f);
    float poly = t * (0.254829592f + t * (-0.284496736f + t * (1.421413741f +
                 t * (-1.453152027f + t * 1.061405429f))));
    float e = fexp2(-ax * ax * 1.4426950408889634f);
    float erfv = 1.f - poly * e;
    erfv = copysignf(erfv, x);
    return 0.5f * v * (1.f + erfv);
}

// ---------------- f32 -> bf16 conversion (vectorized) ----------------
__global__ __launch_bounds__(256) void cvt_k(const float* __restrict__ in,
                                             bf16* __restrict__ out, int n4)
{
    int i = blockIdx.x * 256 + threadIdx.x;
    if (i >= n4) return;
    float4 v = reinterpret_cast<const float4*>(in)[i];
    bf16x4 o;
    o[0] = (bf16)v.x; o[1] = (bf16)v.y; o[2] = (bf16)v.z; o[3] = (bf16)v.w;
    reinterpret_cast<bf16x4*>(out)[i] = o;
}

// ---------------- embedding ----------------
__global__ void embed_k(const int* __restrict__ src, const float* __restrict__ emb,
                        const float* __restrict__ cls, float* __restrict__ x,
                        bf16* __restrict__ xb)
{
    long i = (long)blockIdx.x * blockDim.x + threadIdx.x;
    if (i >= (long)B * L * D) return;
    int d = (int)(i % D);
    long bl = i / D;
    int l = (int)(bl % L);
    int b = (int)(bl / L);
    float v = (l == 0) ? cls[d] : emb[(long)src[b * S + (l - 1)] * D + d];
    x[i] = v;
    xb[i] = (bf16)v;
}

// ---------------- MFMA bf16 GEMM, 2-phase double-buffered LDS (R14) ----------
template<int ACT, int OBF, int BIAS, int RT>
__global__ __launch_bounds__(256) void mgemm(const bf16* __restrict__ A,
                                             const bf16* __restrict__ W,
                                             const float* __restrict__ bias,
                                             float* __restrict__ Cf,
                                             bf16* __restrict__ Cb,
                                             int N, int K, int LDA)
{
    __shared__ bf16 Asl[2][RT * 32];
    __shared__ bf16 Bsl[2][128 * 32];
    int tid = threadIdx.x;
    int m0 = blockIdx.y * RT;
    int n0 = blockIdx.x * 128;
    int lane = tid & 63;
    int w = tid >> 6;
    int wbase = tid & ~63;
    int kb = (lane >> 4) * 8;
    int rsel = lane & 15;
    constexpr int FJ = (RT == 128) ? 4 : 2;
    constexpr int CW = (RT == 128) ? 64 : 32;
    int wr, wc;
    if constexpr (RT == 128) { wr = w >> 1; wc = w & 1; }
    else                     { wr = 0;      wc = w;     }
    f32x4 acc[4][FJ] = {};

    auto stage = [&](int buf, int k0) {
        if constexpr (RT == 128) {
#pragma unroll
            for (int r = 0; r < 2; r++) {
                int s = r * 256 + tid;
                int sb = r * 256 + wbase;
                gld16(A + (size_t)(m0 + (s >> 2)) * LDA + k0 + (s & 3) * 8, &Asl[buf][(size_t)sb * 8]);
                gld16(W + (size_t)(n0 + (s >> 2)) * LDA + k0 + (s & 3) * 8, &Bsl[buf][(size_t)sb * 8]);
            }
        } else {
            gld16(A + (size_t)(m0 + (tid >> 2)) * LDA + k0 + (tid & 3) * 8, &Asl[buf][(size_t)wbase * 8]);
#pragma unroll
            for (int r = 0; r < 2; r++) {
                int s = r * 256 + tid;
                int sb = r * 256 + wbase;
                gld16(W + (size_t)(n0 + (s >> 2)) * LDA + k0 + (s & 3) * 8, &Bsl[buf][(size_t)sb * 8]);
            }
        }
    };

    stage(0, 0);
    __syncthreads();

    for (int k0 = 0; k0 < K; k0 += 32) {
        int cur = (k0 >> 5) & 1;
        if (k0 + 32 < K) stage(cur ^ 1, k0 + 32);
        bf16x8 af[4], bfr[FJ];
#pragma unroll
        for (int fi = 0; fi < 4; fi++)
            af[fi] = *reinterpret_cast<const bf16x8*>(&Asl[cur][(wr * 64 + fi * 16 + rsel) * 32 + kb]);
#pragma unroll
        for (int fj = 0; fj < FJ; fj++)
            bfr[fj] = *reinterpret_cast<const bf16x8*>(&Bsl[cur][(wc * CW + fj * 16 + rsel) * 32 + kb]);
#pragma unroll
        for (int fi = 0; fi < 4; fi++)
#pragma unroll
            for (int fj = 0; fj < FJ; fj++)
                acc[fi][fj] = __builtin_amdgcn_mfma_f32_16x16x32_bf16(af[fi], bfr[fj], acc[fi][fj], 0, 0, 0);
        __syncthreads();
    }
    int rowb = (lane >> 4) * 4;
    int colb = lane & 15;
#pragma unroll
    for (int fi = 0; fi < 4; fi++) {
#pragma unroll
        for (int fj = 0; fj < FJ; fj++) {
            int col = n0 + wc * CW + fj * 16 + colb;
            float bsv = BIAS ? bias[col] : 0.f;
#pragma unroll
            for (int i = 0; i < 4; i++) {
                int row = m0 + wr * 64 + fi * 16 + rowb + i;
                float v = acc[fi][fj][i] + bsv;
                if (ACT) v = fast_gelu(v);
                if (OBF) Cb[(size_t)row * N + col] = (bf16)v;
                else     Cf[(size_t)row * N + col] = v;
            }
        }
    }
}

// ---------------- MFMA flash attention v8: triple-buffered Vt, 1 barrier/tile -
// v7 structure (2 q-tiles share K/V pipeline). D2 removed: Vt has 3 buffers,
// so the write at tile t (buf (t+1)%3, pre-barrier) and the last reads of that
// buffer (tile t-2 PV, post-D1(t-2)) are separated by D1(t-1). colm ping-pong:
// within a tile read/write indices differ; cross-tile pairs separated by D1.
// Psh is wave-private (same-wave LDS ordering suffices).
__global__ __launch_bounds__(256) void fattn_k(const bf16* __restrict__ qkv,
                                               const float* __restrict__ rel_emb_l,
                                               const unsigned char* __restrict__ pad,
                                               bf16* __restrict__ ob)
{
    constexpr int PIT = 72;
    __shared__ bf16 Vt[3][64 * PIT];       // V^T[d][k ^ ((d>>3)<<3)], triple buffer
    __shared__ bf16 Psh[4][2][16 * PIT];   // per-wave, per-qq P[q][kv]
    __shared__ float bias2s[2 * MAXD + 1];
    __shared__ float colm[2][64];

    const int bh = blockIdx.x;
    const int qt = blockIdx.y;
    const int h = bh & 7, b = bh >> 3;
    const int q0 = qt * 128;
    const int tid = threadIdx.x;
    const int lane = tid & 63;
    const int w = tid >> 6;
    const int ln15 = lane & 15, g4 = lane >> 4;
    const int kb8 = g4 * 8;
    constexpr float LOG2E = 1.4426950408889634f;
    constexpr float C2 = 0.125f * LOG2E;

    const char* base = (const char*)qkv + (size_t)(b * L) * 3072 + (size_t)h * (HD * 2);

    for (int i = tid; i < 2 * MAXD + 1; i += 256) bias2s[i] = rel_emb_l[i * H + h] * LOG2E;
    if (tid < 64) colm[0][tid] = (tid > 0 && pad[(size_t)b * S + tid - 1]) ? -1e9f : 0.f;

    int qrow[2];
    bf16x8 qa[2][2];
#pragma unroll
    for (int qq = 0; qq < 2; qq++) {
        qrow[qq] = q0 + qq * 64 + w * 16 + ln15;
        qa[qq][0] = *(const bf16x8*)(base + (size_t)qrow[qq] * 3072 + g4 * 16);
        qa[qq][1] = *(const bf16x8*)(base + (size_t)qrow[qq] * 3072 + 64 + g4 * 16);
    }

    const int vr = tid >> 3;
    const int vd0 = (tid & 7) * 8;
    const int vsw = ((vd0 >> 3) & 7) << 3;

    { // prologue: stage V tile 0 into Vt[0]
        bf16x8 a = *(const bf16x8*)(base + (size_t)vr * 3072 + 2048 + vd0 * 2);
        bf16x8 c = *(const bf16x8*)(base + (size_t)(vr + 32) * 3072 + 2048 + vd0 * 2);
#pragma unroll
        for (int j = 0; j < 8; j++) {
            Vt[0][(vd0 + j) * PIT + (vr ^ vsw)] = a[j];
            Vt[0][(vd0 + j) * PIT + ((vr + 32) ^ vsw)] = c[j];
        }
    }
    bf16x8 kr[4][2];
#pragma unroll
    for (int fj = 0; fj < 4; fj++) {
        const char* rp = base + (size_t)(fj * 16 + ln15) * 3072 + 1024 + g4 * 16;
        kr[fj][0] = *(const bf16x8*)(rp);
        kr[fj][1] = *(const bf16x8*)(rp + 64);
    }
    LGKM_BARRIER();

    f32x4 oacc[2][4] = {};
    float m_prev[2] = {-1e30f, -1e30f};
    float l_sum[2] = {0.f, 0.f};

    int cur3 = 0;
    for (int t = 0; t < 17; t++) {
        const int k0 = t * 64;
        const int k0n = (k0 + 64 > 1024) ? 1024 : (k0 + 64);
        const int curM = t & 1;   // colm index
        int nxt3 = cur3 + 1; if (nxt3 == 3) nxt3 = 0;

        bf16x8 vA = *(const bf16x8*)(base + (size_t)(k0n + vr) * 3072 + 2048 + vd0 * 2);
        bf16x8 vB = *(const bf16x8*)(base + (size_t)(k0n + vr + 32) * 3072 + 2048 + vd0 * 2);

        f32x4 sacc[2][4] = {};
#pragma unroll
        for (int qq = 0; qq < 2; qq++)
#pragma unroll
            for (int fj = 0; fj < 4; fj++) {
                sacc[qq][fj] = __builtin_amdgcn_mfma_f32_16x16x32_bf16(kr[fj][0], qa[qq][0], sacc[qq][fj], 0, 0, 0);
                sacc[qq][fj] = __builtin_amdgcn_mfma_f32_16x16x32_bf16(kr[fj][1], qa[qq][1], sacc[qq][fj], 0, 0, 0);
            }
#pragma unroll
        for (int fj = 0; fj < 4; fj++) {
            const char* rp = base + (size_t)(k0n + fj * 16 + ln15) * 3072 + 1024 + g4 * 16;
            kr[fj][0] = *(const bf16x8*)(rp);
            kr[fj][1] = *(const bf16x8*)(rp + 64);
        }

        f32x4 cm[4];
#pragma unroll
        for (int fj = 0; fj < 4; fj++)
            cm[fj] = *(const f32x4*)&colm[curM][fj * 16 + g4 * 4];

#pragma unroll
        for (int qq = 0; qq < 2; qq++) {
            float sv[4][4];
            const int relbw = k0 - q0 - qq * 64 - w * 16;
            if (relbw >= MAXD + 15 || relbw <= -MAXD - 63) {
                const float bu = bias2s[relbw > 0 ? 2 * MAXD : 0];
#pragma unroll
                for (int fj = 0; fj < 4; fj++)
#pragma unroll
                    for (int i = 0; i < 4; i++)
                        sv[fj][i] = fmaf(sacc[qq][fj][i], C2, bu + cm[fj][i]);
            } else {
                const int relb = k0 - qrow[qq];
#pragma unroll
                for (int fj = 0; fj < 4; fj++)
#pragma unroll
                    for (int i = 0; i < 4; i++) {
                        int rel = relb + fj * 16 + g4 * 4 + i;
                        rel = rel < -MAXD ? -MAXD : (rel > MAXD ? MAXD : rel);
                        sv[fj][i] = fmaf(sacc[qq][fj][i], C2, bias2s[rel + MAXD] + cm[fj][i]);
                    }
            }

            float mx = sv[0][0];
#pragma unroll
            for (int fj = 0; fj < 4; fj++)
#pragma unroll
                for (int i = 0; i < 4; i++) mx = fmaxf(mx, sv[fj][i]);
            mx = fmaxf(mx, __shfl_xor(mx, 16));
            mx = fmaxf(mx, __shfl_xor(mx, 32));
            const float mnew = fmaxf(m_prev[qq], mx);
            const float corr = fexp2(m_prev[qq] - mnew);
            float rsum = 0.f;
            float pb[4][4];
#pragma unroll
            for (int fj = 0; fj < 4; fj++)
#pragma unroll
                for (int i = 0; i < 4; i++) {
                    float p = fexp2(sv[fj][i] - mnew);
                    pb[fj][i] = p;
                    rsum += p;
                }
            rsum += __shfl_xor(rsum, 16);
            rsum += __shfl_xor(rsum, 32);
            l_sum[qq] = l_sum[qq] * corr + rsum;
            m_prev[qq] = mnew;
#pragma unroll
            for (int fd = 0; fd < 4; fd++) oacc[qq][fd] *= corr;

#pragma unroll
            for (int fj = 0; fj < 4; fj++) {
                union { bf16 hh[4]; unsigned long long u; } pk;
                pk.hh[0] = (bf16)pb[fj][0]; pk.hh[1] = (bf16)pb[fj][1];
                pk.hh[2] = (bf16)pb[fj][2]; pk.hh[3] = (bf16)pb[fj][3];
                *(unsigned long long*)&Psh[w][qq][ln15 * PIT + fj * 16 + g4 * 4] = pk.u;
            }
        }

        // commit next V tile into Vt[nxt3] + next colm
#pragma unroll
        for (int j = 0; j < 8; j++) {
            Vt[nxt3][(vd0 + j) * PIT + (vr ^ vsw)] = vA[j];
            Vt[nxt3][(vd0 + j) * PIT + ((vr + 32) ^ vsw)] = vB[j];
        }
        if (tid < 64) {
            int gk = k0 + 64 + tid;
            int pi = (gk <= 1024) ? gk - 1 : 0;
            colm[curM ^ 1][tid] = (gk > 1024 || pad[(size_t)b * S + pi]) ? -1e9f : 0.f;
        }

        LGKM_BARRIER();   // single barrier per tile

        bf16x8 pa[2][2];
#pragma unroll
        for (int qq = 0; qq < 2; qq++) {
            pa[qq][0] = *(const bf16x8*)&Psh[w][qq][ln15 * PIT + kb8];
            pa[qq][1] = *(const bf16x8*)&Psh[w][qq][ln15 * PIT + 32 + kb8];
        }
#pragma unroll
        for (int fd = 0; fd < 4; fd++) {
            const int d = fd * 16 + ln15;
            const int vx = ((d >> 3) & 7) << 3;
            bf16x8 af0 = *(const bf16x8*)&Vt[cur3][d * PIT + (kb8 ^ vx)];
            bf16x8 af1 = *(const bf16x8*)&Vt[cur3][d * PIT + ((32 + kb8) ^ vx)];
            oacc[0][fd] = __builtin_amdgcn_mfma_f32_16x16x32_bf16(af0, pa[0][0], oacc[0][fd], 0, 0, 0);
            oacc[0][fd] = __builtin_amdgcn_mfma_f32_16x16x32_bf16(af1, pa[0][1], oacc[0][fd], 0, 0, 0);
            oacc[1][fd] = __builtin_amdgcn_mfma_f32_16x16x32_bf16(af0, pa[1][0], oacc[1][fd], 0, 0, 0);
            oacc[1][fd] = __builtin_amdgcn_mfma_f32_16x16x32_bf16(af1, pa[1][1], oacc[1][fd], 0, 0, 0);
        }
        cur3 = nxt3;
    }

#pragma unroll
    for (int qq = 0; qq < 2; qq++) {
        if (qrow[qq] < L) {
            const float inv = 1.f / l_sum[qq];
            bf16* op = ob + (size_t)(b * L + qrow[qq]) * D + h * HD + g4 * 4;
#pragma unroll
            for (int fd = 0; fd < 4; fd++) {
                bf16x4 r;
#pragma unroll
                for (int i = 0; i < 4; i++) r[i] = (bf16)(oacc[qq][fd][i] * inv);
                *(bf16x4*)(op + fd * 16) = r;
            }
        }
    }
}

// ---------------- out = LayerNorm(xin + rin), f32 + bf16 copies ----------------
__global__ __launch_bounds__(256) void add_ln_k(const float* __restrict__ xin,
                                                const float* __restrict__ rin,
                                                const float* __restrict__ g,
                                                const float* __restrict__ bb,
                                                float* __restrict__ out,
                                                bf16* __restrict__ outb)
{
    int row = blockIdx.x;
    __shared__ float red[8];
    int tid = threadIdx.x;
    const float* xp = xin + (size_t)row * D;
    const float* rp = rin + (size_t)row * D;
    float v0 = xp[tid] + rp[tid];
    float v1 = xp[tid + 256] + rp[tid + 256];
    float s = v0 + v1;
    for (int off = 32; off; off >>= 1) s += __shfl_down(s, off, 64);
    int lane = tid & 63, wid = tid >> 6;
    if (lane == 0) red[wid] = s;
    __syncthreads();
    if (tid == 0) red[0] = red[0] + red[1] + red[2] + red[3];
    __syncthreads();
    float mean = red[0] * (1.f / D);
    float d0 = v0 - mean, d1 = v1 - mean;
    float sq = d0 * d0 + d1 * d1;
    for (int off = 32; off; off >>= 1) sq += __shfl_down(sq, off, 64);
    if (lane == 0) red[4 + wid] = sq;
    __syncthreads();
    if (tid == 0) red[4] = red[4] + red[5] + red[6] + red[7];
    __syncthreads();
    float rs = rsqrtf(red[4] * (1.f / D) + 1e-5f);
    float r0 = d0 * rs * g[tid] + bb[tid];
    float r1 = d1 * rs * g[tid + 256] + bb[tid + 256];
    out[(size_t)row * D + tid] = r0;
    out[(size_t)row * D + tid + 256] = r1;
    outb[(size_t)row * D + tid] = (bf16)r0;
    outb[(size_t)row * D + tid + 256] = (bf16)r1;
}

// ---------------- final LN (row 0 only) + classifier ----------------
__global__ __launch_bounds__(256) void cls_k(const float* __restrict__ x,
                                             const float* __restrict__ ng,
                                             const float* __restrict__ nb,
                                             const float* __restrict__ cw,
                                             const float* __restrict__ cb,
                                             float* __restrict__ out)
{
    int b = blockIdx.x;
    __shared__ float xn[D];
    __shared__ float red[8];
    int tid = threadIdx.x;
    const float* xp = x + (size_t)(b * L) * D;
    float v0 = xp[tid], v1 = xp[tid + 256];
    float s = v0 + v1;
    for (int off = 32; off; off >>= 1) s += __shfl_down(s, off, 64);
    int lane = tid & 63, wid = tid >> 6;
    if (lane == 0) red[wid] = s;
    __syncthreads();
    if (tid == 0) red[0] = red[0] + red[1] + red[2] + red[3];
    __syncthreads();
    float mean = red[0] * (1.f / D);
    float d0 = v0 - mean, d1 = v1 - mean;
    float sq = d0 * d0 + d1 * d1;
    for (int off = 32; off; off >>= 1) sq += __shfl_down(sq, off, 64);
    if (lane == 0) red[4 + wid] = sq;
    __syncthreads();
    if (tid == 0) red[4] = red[4] + red[5] + red[6] + red[7];
    __syncthreads();
    float rs = rsqrtf(red[4] * (1.f / D) + 1e-5f);
    xn[tid] = d0 * rs * ng[tid] + nb[tid];
    xn[tid + 256] = d1 * rs * ng[tid + 256] + nb[tid + 256];
    __syncthreads();
    for (int o = tid; o < OUTLEN * NC; o += 256) {
        float acc = cb[o];
        const float* wp = cw + (size_t)o * D;
        for (int d = 0; d < D; d++) acc += xn[d] * wp[d];
        out[b * OUTLEN * NC + o] = acc;
    }
}

extern "C" void kernel_launch(void* const* d_in, const int* in_sizes, int n_in,
                              void* d_out, int out_size, void* d_ws, size_t ws_size,
                              hipStream_t stream) {
    const int* src = (const int*)d_in[0];
    const unsigned char* pad = (const unsigned char*)d_in[1];
    const float* emb = (const float*)d_in[2];
    const float* cls_token = (const float*)d_in[3];
    const float* qkv_w = (const float*)d_in[4];
    const float* qkv_b = (const float*)d_in[5];
    const float* out_w = (const float*)d_in[6];
    const float* out_b = (const float*)d_in[7];
    const float* rel_emb = (const float*)d_in[8];
    const float* ln1_g = (const float*)d_in[9];
    const float* ln1_b = (const float*)d_in[10];
    const float* w1 = (const float*)d_in[11];
    const float* b1 = (const float*)d_in[12];
    const float* w2 = (const float*)d_in[13];
    const float* b2 = (const float*)d_in[14];
    const float* ln2_g = (const float*)d_in[15];
    const float* ln2_b = (const float*)d_in[16];
    const float* norm_g = (const float*)d_in[17];
    const float* norm_b = (const float*)d_in[18];
    const float* cls_w = (const float*)d_in[19];
    const float* cls_b = (const float*)d_in[20];
    float* out = (float*)d_out;

    char* ws = (char*)d_ws;
    size_t off = 0;
    float* x   = (float*)(ws + off); off += (size_t)MP * D * 4;
    bf16*  xb  = (bf16*) (ws + off); off += (size_t)MP * D * 2;
    float* x2  = (float*)(ws + off); off += (size_t)MP * D * 4;
    bf16*  x2b = (bf16*) (ws + off); off += (size_t)MP * D * 2;
    char*  R   = ws + off;           off += (size_t)MP * 3 * D * 4; // qkvb | (hb + p)
    bf16*  qkvb = (bf16*)R;                              // MP*3D*2
    bf16*  hb  = (bf16*)R;                               // MP*FF*2 (after attn)
    float* p   = (float*)(R + (size_t)MP * FF * 2);      // MP*D*4
    bf16*  obf = (bf16*) (ws + off); off += (size_t)MP * D * 2;

    const size_t WQ = (size_t)NL * 3 * D * D;
    const size_t WO = (size_t)NL * D * D;
    const size_t W1E = (size_t)NL * FF * D;
    const size_t W2E = (size_t)NL * D * FF;
    const size_t WALL = WQ + WO + W1E + W2E;
    bool all_w = (off + WALL * 2) <= ws_size;

    bf16 *wq_a = nullptr, *wo_a = nullptr, *w1_a = nullptr, *w2_a = nullptr, *wbuf = nullptr;
    if (all_w) {
        wq_a = (bf16*)(ws + off);
        wo_a = wq_a + WQ;
        w1_a = wo_a + WO;
        w2_a = w1_a + W1E;
        int n4;
        n4 = (int)(WQ / 4);  cvt_k<<<dim3((n4 + 255) / 256), 256, 0, stream>>>(qkv_w, wq_a, n4);
        n4 = (int)(WO / 4);  cvt_k<<<dim3((n4 + 255) / 256), 256, 0, stream>>>(out_w, wo_a, n4);
        n4 = (int)(W1E / 4); cvt_k<<<dim3((n4 + 255) / 256), 256, 0, stream>>>(w1, w1_a, n4);
        n4 = (int)(W2E / 4); cvt_k<<<dim3((n4 + 255) / 256), 256, 0, stream>>>(w2, w2_a, n4);
    } else {
        wbuf = (bf16*)(ws + off); // per-layer rotating buffer
    }

    const int M = B * L;
    {
        long total = (long)B * L * D;
        embed_k<<<dim3((unsigned)((total + 255) / 256)), 256, 0, stream>>>(src, emb, cls_token, x, xb);
    }
    for (int l = 0; l < NL; l++) {
        const float* qb  = qkv_b + (size_t)l * 3 * D;
        const float* obi = out_b + (size_t)l * D;
        const float* re  = rel_emb + (size_t)l * (2 * MAXD + 1) * H;
        const float* g1  = ln1_g + (size_t)l * D;
        const float* be1 = ln1_b + (size_t)l * D;
        const float* B1p = b1 + (size_t)l * FF;
        const float* B2p = b2 + (size_t)l * D;
        const float* g2  = ln2_g + (size_t)l * D;
        const float* be2 = ln2_b + (size_t)l * D;

        const bf16 *wqb, *wob, *w1b, *w2b;
        if (all_w) {
            wqb = wq_a + (size_t)l * 3 * D * D;
            wob = wo_a + (size_t)l * D * D;
            w1b = w1_a + (size_t)l * FF * D;
            w2b = w2_a + (size_t)l * D * FF;
        } else {
            bf16* wp_ = wbuf;
            wqb = wp_;            wp_ += 3 * D * D;
            wob = wp_;            wp_ += D * D;
            w1b = wp_;            wp_ += FF * D;
            w2b = wp_;
            int n4;
            n4 = 3 * D * D / 4; cvt_k<<<dim3((n4 + 255) / 256), 256, 0, stream>>>(qkv_w + (size_t)l * 3 * D * D, (bf16*)wqb, n4);
            n4 = D * D / 4;     cvt_k<<<dim3((n4 + 255) / 256), 256, 0, stream>>>(out_w + (size_t)l * D * D, (bf16*)wob, n4);
            n4 = FF * D / 4;    cvt_k<<<dim3((n4 + 255) / 256), 256, 0, stream>>>(w1 + (size_t)l * FF * D, (bf16*)w1b, n4);
            n4 = D * FF / 4;    cvt_k<<<dim3((n4 + 255) / 256), 256, 0, stream>>>(w2 + (size_t)l * D * FF, (bf16*)w2b, n4);
        }

        mgemm<0, 1, 1, 128><<<dim3(3 * D / 128, MP / 128), 256, 0, stream>>>(xb, wqb, qb, nullptr, qkvb, 3 * D, D, D);
        fattn_k<<<dim3(B * H, 9), 256, 0, stream>>>(qkvb, re, pad, obf);
        mgemm<0, 0, 1, 64><<<dim3(D / 128, MP / 64), 256, 0, stream>>>(obf, wob, obi, p, nullptr, D, D, D);
        add_ln_k<<<dim3(M), 256, 0, stream>>>(x, p, g1, be1, x2, x2b);
        mgemm<1, 1, 1, 128><<<dim3(FF / 128, MP / 128), 256, 0, stream>>>(x2b, w1b, B1p, nullptr, hb, FF, D, D);
        mgemm<0, 0, 1, 64><<<dim3(D / 128, MP / 64), 256, 0, stream>>>(hb, w2b, B2p, p, nullptr, D, FF, FF);
        add_ln_k<<<dim3(M), 256, 0, stream>>>(x2, p, g2, be2, x, xb);
    }
    cls_k<<<dim3(B), 256, 0, stream>>>(x, norm_g, norm_b, cls_w, cls_b, out);
}

// Round 18
// 1462.866 us; speedup vs baseline: 1.3622x; 1.0083x over previous
//
#include <hip/hip_runtime.h>
#include <hip/hip_bf16.h>
#include <stdint.h>

#define B 8
#define S 1024
#define L 1025
#define D 512
#define H 8
#define HD 64
#define NL 6
#define FF 2048
#define MAXD 64
#define OUTLEN 8
#define NC 10

#define MP 8320   // 65 * 128, padded M

typedef __bf16 bf16;
typedef __bf16 bf16x8 __attribute__((ext_vector_type(8)));
typedef __bf16 bf16x4 __attribute__((ext_vector_type(4)));
typedef float f32x4 __attribute__((ext_vector_type(4)));

__device__ __forceinline__ float fexp2(float x) { return __builtin_amdgcn_exp2f(x); }

// barrier WITHOUT the vmcnt(0) drain
#define LGKM_BARRIER() asm volatile("s_waitcnt lgkmcnt(0)\ns_barrier" ::: "memory")

__device__ __forceinline__ void gld16(const void* g, void* l) {
    __builtin_amdgcn_global_load_lds(
        (const __attribute__((address_space(1))) unsigned int*)g,
        (__attribute__((address_space(3))) unsigned int*)l,
        16, 0, 0);
}

// GELU with A&S 7.1.26 erf (|err| <= 1.5e-7), no libm call
__device__ __forceinline__ float fast_gelu(float v) {
    float x = v * 0.70710678118654752f;
    float ax = fabsf(x);
    float t = 1.f / fmaf(0.3275911f, ax, 1.f);
    float poly = t * (0.254829592f + t * (-0.284496736f + t * (1.421413741f +
                 t * (-1.453152027f + t * 1.061405429f))));
    float e = fexp2(-ax * ax * 1.4426950408889634f);
    float erfv = 1.f - poly * e;
    erfv = copysignf(erfv, x);
    return 0.5f * v * (1.f + erfv);
}

// ---------------- f32 -> bf16 conversion (vectorized) ----------------
__global__ __launch_bounds__(256) void cvt_k(const float* __restrict__ in,
                                             bf16* __restrict__ out, int n4)
{
    int i = blockIdx.x * 256 + threadIdx.x;
    if (i >= n4) return;
    float4 v = reinterpret_cast<const float4*>(in)[i];
    bf16x4 o;
    o[0] = (bf16)v.x; o[1] = (bf16)v.y; o[2] = (bf16)v.z; o[3] = (bf16)v.w;
    reinterpret_cast<bf16x4*>(out)[i] = o;
}

// ---------------- embedding ----------------
__global__ void embed_k(const int* __restrict__ src, const float* __restrict__ emb,
                        const float* __restrict__ cls, float* __restrict__ x,
                        bf16* __restrict__ xb)
{
    long i = (long)blockIdx.x * blockDim.x + threadIdx.x;
    if (i >= (long)B * L * D) return;
    int d = (int)(i % D);
    long bl = i / D;
    int l = (int)(bl % L);
    int b = (int)(bl / L);
    float v = (l == 0) ? cls[d] : emb[(long)src[b * S + (l - 1)] * D + d];
    x[i] = v;
    xb[i] = (bf16)v;
}

// ---------------- MFMA bf16 GEMM, 2-phase double-buffered LDS (R14) ----------
template<int ACT, int OBF, int BIAS, int RT>
__global__ __launch_bounds__(256) void mgemm(const bf16* __restrict__ A,
                                             const bf16* __restrict__ W,
                                             const float* __restrict__ bias,
                                             float* __restrict__ Cf,
                                             bf16* __restrict__ Cb,
                                             int N, int K, int LDA)
{
    __shared__ bf16 Asl[2][RT * 32];
    __shared__ bf16 Bsl[2][128 * 32];
    int tid = threadIdx.x;
    int m0 = blockIdx.y * RT;
    int n0 = blockIdx.x * 128;
    int lane = tid & 63;
    int w = tid >> 6;
    int wbase = tid & ~63;
    int kb = (lane >> 4) * 8;
    int rsel = lane & 15;
    constexpr int FJ = (RT == 128) ? 4 : 2;
    constexpr int CW = (RT == 128) ? 64 : 32;
    int wr, wc;
    if constexpr (RT == 128) { wr = w >> 1; wc = w & 1; }
    else                     { wr = 0;      wc = w;     }
    f32x4 acc[4][FJ] = {};

    auto stage = [&](int buf, int k0) {
        if constexpr (RT == 128) {
#pragma unroll
            for (int r = 0; r < 2; r++) {
                int s = r * 256 + tid;
                int sb = r * 256 + wbase;
                gld16(A + (size_t)(m0 + (s >> 2)) * LDA + k0 + (s & 3) * 8, &Asl[buf][(size_t)sb * 8]);
                gld16(W + (size_t)(n0 + (s >> 2)) * LDA + k0 + (s & 3) * 8, &Bsl[buf][(size_t)sb * 8]);
            }
        } else {
            gld16(A + (size_t)(m0 + (tid >> 2)) * LDA + k0 + (tid & 3) * 8, &Asl[buf][(size_t)wbase * 8]);
#pragma unroll
            for (int r = 0; r < 2; r++) {
                int s = r * 256 + tid;
                int sb = r * 256 + wbase;
                gld16(W + (size_t)(n0 + (s >> 2)) * LDA + k0 + (s & 3) * 8, &Bsl[buf][(size_t)sb * 8]);
            }
        }
    };

    stage(0, 0);
    __syncthreads();

    for (int k0 = 0; k0 < K; k0 += 32) {
        int cur = (k0 >> 5) & 1;
        if (k0 + 32 < K) stage(cur ^ 1, k0 + 32);
        bf16x8 af[4], bfr[FJ];
#pragma unroll
        for (int fi = 0; fi < 4; fi++)
            af[fi] = *reinterpret_cast<const bf16x8*>(&Asl[cur][(wr * 64 + fi * 16 + rsel) * 32 + kb]);
#pragma unroll
        for (int fj = 0; fj < FJ; fj++)
            bfr[fj] = *reinterpret_cast<const bf16x8*>(&Bsl[cur][(wc * CW + fj * 16 + rsel) * 32 + kb]);
#pragma unroll
        for (int fi = 0; fi < 4; fi++)
#pragma unroll
            for (int fj = 0; fj < FJ; fj++)
                acc[fi][fj] = __builtin_amdgcn_mfma_f32_16x16x32_bf16(af[fi], bfr[fj], acc[fi][fj], 0, 0, 0);
        __syncthreads();
    }
    int rowb = (lane >> 4) * 4;
    int colb = lane & 15;
#pragma unroll
    for (int fi = 0; fi < 4; fi++) {
#pragma unroll
        for (int fj = 0; fj < FJ; fj++) {
            int col = n0 + wc * CW + fj * 16 + colb;
            float bsv = BIAS ? bias[col] : 0.f;
#pragma unroll
            for (int i = 0; i < 4; i++) {
                int row = m0 + wr * 64 + fi * 16 + rowb + i;
                float v = acc[fi][fj][i] + bsv;
                if (ACT) v = fast_gelu(v);
                if (OBF) Cb[(size_t)row * N + col] = (bf16)v;
                else     Cf[(size_t)row * N + col] = v;
            }
        }
    }
}

// ---------------- MFMA flash attention v9: KV-split (2 halves) ---------------
// v8 tile body (2 q-subtiles, triple-buffered Vt, 1 barrier/tile). blockIdx.z
// selects KV half: z=0 -> tiles [0,9), z=1 -> tiles [9,17). Epilogue stores
// NORMALIZED partial O (bf16, convex comb of V rows -> O(1)) + (m,l) float2.
__global__ __launch_bounds__(256) void fattn_k(const bf16* __restrict__ qkv,
                                               const float* __restrict__ rel_emb_l,
                                               const unsigned char* __restrict__ pad,
                                               bf16* __restrict__ op0,
                                               bf16* __restrict__ op1,
                                               float2* __restrict__ mlout)
{
    constexpr int PIT = 72;
    __shared__ bf16 Vt[3][64 * PIT];
    __shared__ bf16 Psh[4][2][16 * PIT];
    __shared__ float bias2s[2 * MAXD + 1];
    __shared__ float colm[2][64];

    const int bh = blockIdx.x;
    const int qt = blockIdx.y;
    const int z = blockIdx.z;
    const int tbeg = z ? 9 : 0;
    const int tend = z ? 17 : 9;
    bf16* opart = z ? op1 : op0;
    const int h = bh & 7, b = bh >> 3;
    const int q0 = qt * 128;
    const int tid = threadIdx.x;
    const int lane = tid & 63;
    const int w = tid >> 6;
    const int ln15 = lane & 15, g4 = lane >> 4;
    const int kb8 = g4 * 8;
    constexpr float LOG2E = 1.4426950408889634f;
    constexpr float C2 = 0.125f * LOG2E;

    const char* base = (const char*)qkv + (size_t)(b * L) * 3072 + (size_t)h * (HD * 2);

    for (int i = tid; i < 2 * MAXD + 1; i += 256) bias2s[i] = rel_emb_l[i * H + h] * LOG2E;
    if (tid < 64) {
        int gk0 = tbeg * 64 + tid;
        int pi = (gk0 > 0 && gk0 <= 1024) ? gk0 - 1 : 0;
        colm[tbeg & 1][tid] = (gk0 > 1024 || (gk0 > 0 && pad[(size_t)b * S + pi])) ? -1e9f : 0.f;
    }

    int qrow[2];
    bf16x8 qa[2][2];
#pragma unroll
    for (int qq = 0; qq < 2; qq++) {
        qrow[qq] = q0 + qq * 64 + w * 16 + ln15;
        qa[qq][0] = *(const bf16x8*)(base + (size_t)qrow[qq] * 3072 + g4 * 16);
        qa[qq][1] = *(const bf16x8*)(base + (size_t)qrow[qq] * 3072 + 64 + g4 * 16);
    }

    const int vr = tid >> 3;
    const int vd0 = (tid & 7) * 8;
    const int vsw = ((vd0 >> 3) & 7) << 3;

    { // prologue: stage V tile tbeg into Vt[0]
        int kv0 = tbeg * 64;
        bf16x8 a = *(const bf16x8*)(base + (size_t)(kv0 + vr) * 3072 + 2048 + vd0 * 2);
        bf16x8 c = *(const bf16x8*)(base + (size_t)(kv0 + vr + 32) * 3072 + 2048 + vd0 * 2);
#pragma unroll
        for (int j = 0; j < 8; j++) {
            Vt[0][(vd0 + j) * PIT + (vr ^ vsw)] = a[j];
            Vt[0][(vd0 + j) * PIT + ((vr + 32) ^ vsw)] = c[j];
        }
    }
    bf16x8 kr[4][2];
#pragma unroll
    for (int fj = 0; fj < 4; fj++) {
        const char* rp = base + (size_t)(tbeg * 64 + fj * 16 + ln15) * 3072 + 1024 + g4 * 16;
        kr[fj][0] = *(const bf16x8*)(rp);
        kr[fj][1] = *(const bf16x8*)(rp + 64);
    }
    LGKM_BARRIER();

    f32x4 oacc[2][4] = {};
    float m_prev[2] = {-1e30f, -1e30f};
    float l_sum[2] = {0.f, 0.f};

    int cur3 = 0;
    for (int t = tbeg; t < tend; t++) {
        const int k0 = t * 64;
        const int k0n = (k0 + 64 > 1024) ? 1024 : (k0 + 64);
        const int curM = t & 1;
        int nxt3 = cur3 + 1; if (nxt3 == 3) nxt3 = 0;

        bf16x8 vA = *(const bf16x8*)(base + (size_t)(k0n + vr) * 3072 + 2048 + vd0 * 2);
        bf16x8 vB = *(const bf16x8*)(base + (size_t)(k0n + vr + 32) * 3072 + 2048 + vd0 * 2);

        f32x4 sacc[2][4] = {};
#pragma unroll
        for (int qq = 0; qq < 2; qq++)
#pragma unroll
            for (int fj = 0; fj < 4; fj++) {
                sacc[qq][fj] = __builtin_amdgcn_mfma_f32_16x16x32_bf16(kr[fj][0], qa[qq][0], sacc[qq][fj], 0, 0, 0);
                sacc[qq][fj] = __builtin_amdgcn_mfma_f32_16x16x32_bf16(kr[fj][1], qa[qq][1], sacc[qq][fj], 0, 0, 0);
            }
#pragma unroll
        for (int fj = 0; fj < 4; fj++) {
            const char* rp = base + (size_t)(k0n + fj * 16 + ln15) * 3072 + 1024 + g4 * 16;
            kr[fj][0] = *(const bf16x8*)(rp);
            kr[fj][1] = *(const bf16x8*)(rp + 64);
        }

        f32x4 cm[4];
#pragma unroll
        for (int fj = 0; fj < 4; fj++)
            cm[fj] = *(const f32x4*)&colm[curM][fj * 16 + g4 * 4];

#pragma unroll
        for (int qq = 0; qq < 2; qq++) {
            float sv[4][4];
            const int relbw = k0 - q0 - qq * 64 - w * 16;
            if (relbw >= MAXD + 15 || relbw <= -MAXD - 63) {
                const float bu = bias2s[relbw > 0 ? 2 * MAXD : 0];
#pragma unroll
                for (int fj = 0; fj < 4; fj++)
#pragma unroll
                    for (int i = 0; i < 4; i++)
                        sv[fj][i] = fmaf(sacc[qq][fj][i], C2, bu + cm[fj][i]);
            } else {
                const int relb = k0 - qrow[qq];
#pragma unroll
                for (int fj = 0; fj < 4; fj++)
#pragma unroll
                    for (int i = 0; i < 4; i++) {
                        int rel = relb + fj * 16 + g4 * 4 + i;
                        rel = rel < -MAXD ? -MAXD : (rel > MAXD ? MAXD : rel);
                        sv[fj][i] = fmaf(sacc[qq][fj][i], C2, bias2s[rel + MAXD] + cm[fj][i]);
                    }
            }

            float mx = sv[0][0];
#pragma unroll
            for (int fj = 0; fj < 4; fj++)
#pragma unroll
                for (int i = 0; i < 4; i++) mx = fmaxf(mx, sv[fj][i]);
            mx = fmaxf(mx, __shfl_xor(mx, 16));
            mx = fmaxf(mx, __shfl_xor(mx, 32));
            const float mnew = fmaxf(m_prev[qq], mx);
            const float corr = fexp2(m_prev[qq] - mnew);
            float rsum = 0.f;
            float pb[4][4];
#pragma unroll
            for (int fj = 0; fj < 4; fj++)
#pragma unroll
                for (int i = 0; i < 4; i++) {
                    float p = fexp2(sv[fj][i] - mnew);
                    pb[fj][i] = p;
                    rsum += p;
                }
            rsum += __shfl_xor(rsum, 16);
            rsum += __shfl_xor(rsum, 32);
            l_sum[qq] = l_sum[qq] * corr + rsum;
            m_prev[qq] = mnew;
#pragma unroll
            for (int fd = 0; fd < 4; fd++) oacc[qq][fd] *= corr;

#pragma unroll
            for (int fj = 0; fj < 4; fj++) {
                union { bf16 hh[4]; unsigned long long u; } pk;
                pk.hh[0] = (bf16)pb[fj][0]; pk.hh[1] = (bf16)pb[fj][1];
                pk.hh[2] = (bf16)pb[fj][2]; pk.hh[3] = (bf16)pb[fj][3];
                *(unsigned long long*)&Psh[w][qq][ln15 * PIT + fj * 16 + g4 * 4] = pk.u;
            }
        }

        // commit next V tile into Vt[nxt3] + next colm
#pragma unroll
        for (int j = 0; j < 8; j++) {
            Vt[nxt3][(vd0 + j) * PIT + (vr ^ vsw)] = vA[j];
            Vt[nxt3][(vd0 + j) * PIT + ((vr + 32) ^ vsw)] = vB[j];
        }
        if (tid < 64) {
            int gk = k0 + 64 + tid;
            int pi = (gk <= 1024) ? gk - 1 : 0;
            colm[curM ^ 1][tid] = (gk > 1024 || pad[(size_t)b * S + pi]) ? -1e9f : 0.f;
        }

        LGKM_BARRIER();   // single barrier per tile

        bf16x8 pa[2][2];
#pragma unroll
        for (int qq = 0; qq < 2; qq++) {
            pa[qq][0] = *(const bf16x8*)&Psh[w][qq][ln15 * PIT + kb8];
            pa[qq][1] = *(const bf16x8*)&Psh[w][qq][ln15 * PIT + 32 + kb8];
        }
#pragma unroll
        for (int fd = 0; fd < 4; fd++) {
            const int d = fd * 16 + ln15;
            const int vx = ((d >> 3) & 7) << 3;
            bf16x8 af0 = *(const bf16x8*)&Vt[cur3][d * PIT + (kb8 ^ vx)];
            bf16x8 af1 = *(const bf16x8*)&Vt[cur3][d * PIT + ((32 + kb8) ^ vx)];
            oacc[0][fd] = __builtin_amdgcn_mfma_f32_16x16x32_bf16(af0, pa[0][0], oacc[0][fd], 0, 0, 0);
            oacc[0][fd] = __builtin_amdgcn_mfma_f32_16x16x32_bf16(af1, pa[0][1], oacc[0][fd], 0, 0, 0);
            oacc[1][fd] = __builtin_amdgcn_mfma_f32_16x16x32_bf16(af0, pa[1][0], oacc[1][fd], 0, 0, 0);
            oacc[1][fd] = __builtin_amdgcn_mfma_f32_16x16x32_bf16(af1, pa[1][1], oacc[1][fd], 0, 0, 0);
        }
        cur3 = nxt3;
    }

    // epilogue: normalized partial O + (m, l) per q-row
#pragma unroll
    for (int qq = 0; qq < 2; qq++) {
        if (qrow[qq] < L) {
            const float inv = 1.f / l_sum[qq];
            bf16* op = opart + (size_t)(b * L + qrow[qq]) * D + h * HD + g4 * 4;
#pragma unroll
            for (int fd = 0; fd < 4; fd++) {
                bf16x4 r;
#pragma unroll
                for (int i = 0; i < 4; i++) r[i] = (bf16)(oacc[qq][fd][i] * inv);
                *(bf16x4*)(op + fd * 16) = r;
            }
            if (g4 == 0)
                mlout[(size_t)(z * 64 + b * 8 + h) * 1025 + qrow[qq]] =
                    make_float2(m_prev[qq], l_sum[qq]);
        }
    }
}

// ---------------- combine the 2 KV-half partials -> obf ----------------
// op1 aliases ob (in-place safe: per-thread read-before-write).
__global__ __launch_bounds__(256) void comb_k(const bf16* __restrict__ op0,
                                              const bf16* __restrict__ op1,
                                              const float2* __restrict__ ml,
                                              bf16* __restrict__ ob)
{
    int row = blockIdx.x;             // b*L + q
    int b = row / L, q = row - b * L;
    int tid = threadIdx.x;
    int d = tid & 63;
    int h0 = tid >> 6;
#pragma unroll
    for (int hh = 0; hh < 2; hh++) {
        int h = h0 + hh * 4;
        float2 a = ml[(size_t)(b * 8 + h) * 1025 + q];
        float2 c = ml[(size_t)(64 + b * 8 + h) * 1025 + q];
        float m = fmaxf(a.x, c.x);
        float s1 = a.y * fexp2(a.x - m);
        float s2 = c.y * fexp2(c.x - m);
        float inv = 1.f / (s1 + s2);
        size_t idx = (size_t)row * D + h * HD + d;
        float o = (s1 * (float)op0[idx] + s2 * (float)op1[idx]) * inv;
        ob[idx] = (bf16)o;
    }
}

// ---------------- out = LayerNorm(xin + rin), f32 + bf16 copies ----------------
__global__ __launch_bounds__(256) void add_ln_k(const float* __restrict__ xin,
                                                const float* __restrict__ rin,
                                                const float* __restrict__ g,
                                                const float* __restrict__ bb,
                                                float* __restrict__ out,
                                                bf16* __restrict__ outb)
{
    int row = blockIdx.x;
    __shared__ float red[8];
    int tid = threadIdx.x;
    const float* xp = xin + (size_t)row * D;
    const float* rp = rin + (size_t)row * D;
    float v0 = xp[tid] + rp[tid];
    float v1 = xp[tid + 256] + rp[tid + 256];
    float s = v0 + v1;
    for (int off = 32; off; off >>= 1) s += __shfl_down(s, off, 64);
    int lane = tid & 63, wid = tid >> 6;
    if (lane == 0) red[wid] = s;
    __syncthreads();
    if (tid == 0) red[0] = red[0] + red[1] + red[2] + red[3];
    __syncthreads();
    float mean = red[0] * (1.f / D);
    float d0 = v0 - mean, d1 = v1 - mean;
    float sq = d0 * d0 + d1 * d1;
    for (int off = 32; off; off >>= 1) sq += __shfl_down(sq, off, 64);
    if (lane == 0) red[4 + wid] = sq;
    __syncthreads();
    if (tid == 0) red[4] = red[4] + red[5] + red[6] + red[7];
    __syncthreads();
    float rs = rsqrtf(red[4] * (1.f / D) + 1e-5f);
    float r0 = d0 * rs * g[tid] + bb[tid];
    float r1 = d1 * rs * g[tid + 256] + bb[tid + 256];
    out[(size_t)row * D + tid] = r0;
    out[(size_t)row * D + tid + 256] = r1;
    outb[(size_t)row * D + tid] = (bf16)r0;
    outb[(size_t)row * D + tid + 256] = (bf16)r1;
}

// ---------------- final LN (row 0 only) + classifier ----------------
__global__ __launch_bounds__(256) void cls_k(const float* __restrict__ x,
                                             const float* __restrict__ ng,
                                             const float* __restrict__ nb,
                                             const float* __restrict__ cw,
                                             const float* __restrict__ cb,
                                             float* __restrict__ out)
{
    int b = blockIdx.x;
    __shared__ float xn[D];
    __shared__ float red[8];
    int tid = threadIdx.x;
    const float* xp = x + (size_t)(b * L) * D;
    float v0 = xp[tid], v1 = xp[tid + 256];
    float s = v0 + v1;
    for (int off = 32; off; off >>= 1) s += __shfl_down(s, off, 64);
    int lane = tid & 63, wid = tid >> 6;
    if (lane == 0) red[wid] = s;
    __syncthreads();
    if (tid == 0) red[0] = red[0] + red[1] + red[2] + red[3];
    __syncthreads();
    float mean = red[0] * (1.f / D);
    float d0 = v0 - mean, d1 = v1 - mean;
    float sq = d0 * d0 + d1 * d1;
    for (int off = 32; off; off >>= 1) sq += __shfl_down(sq, off, 64);
    if (lane == 0) red[4 + wid] = sq;
    __syncthreads();
    if (tid == 0) red[4] = red[4] + red[5] + red[6] + red[7];
    __syncthreads();
    float rs = rsqrtf(red[4] * (1.f / D) + 1e-5f);
    xn[tid] = d0 * rs * ng[tid] + nb[tid];
    xn[tid + 256] = d1 * rs * ng[tid + 256] + nb[tid + 256];
    __syncthreads();
    for (int o = tid; o < OUTLEN * NC; o += 256) {
        float acc = cb[o];
        const float* wp = cw + (size_t)o * D;
        for (int d = 0; d < D; d++) acc += xn[d] * wp[d];
        out[b * OUTLEN * NC + o] = acc;
    }
}

extern "C" void kernel_launch(void* const* d_in, const int* in_sizes, int n_in,
                              void* d_out, int out_size, void* d_ws, size_t ws_size,
                              hipStream_t stream) {
    const int* src = (const int*)d_in[0];
    const unsigned char* pad = (const unsigned char*)d_in[1];
    const float* emb = (const float*)d_in[2];
    const float* cls_token = (const float*)d_in[3];
    const float* qkv_w = (const float*)d_in[4];
    const float* qkv_b = (const float*)d_in[5];
    const float* out_w = (const float*)d_in[6];
    const float* out_b = (const float*)d_in[7];
    const float* rel_emb = (const float*)d_in[8];
    const float* ln1_g = (const float*)d_in[9];
    const float* ln1_b = (const float*)d_in[10];
    const float* w1 = (const float*)d_in[11];
    const float* b1 = (const float*)d_in[12];
    const float* w2 = (const float*)d_in[13];
    const float* b2 = (const float*)d_in[14];
    const float* ln2_g = (const float*)d_in[15];
    const float* ln2_b = (const float*)d_in[16];
    const float* norm_g = (const float*)d_in[17];
    const float* norm_b = (const float*)d_in[18];
    const float* cls_w = (const float*)d_in[19];
    const float* cls_b = (const float*)d_in[20];
    float* out = (float*)d_out;

    char* ws = (char*)d_ws;
    size_t off = 0;
    float* x   = (float*)(ws + off); off += (size_t)MP * D * 4;
    bf16*  xb  = (bf16*) (ws + off); off += (size_t)MP * D * 2;
    float* x2  = (float*)(ws + off); off += (size_t)MP * D * 4;
    bf16*  x2b = (bf16*) (ws + off); off += (size_t)MP * D * 2;
    char*  R   = ws + off;           off += (size_t)MP * 3 * D * 4; // qkvb | (hb + p)
    bf16*  qkvb = (bf16*)R;                              // MP*3D*2
    bf16*  hb  = (bf16*)R;                               // MP*FF*2 (after attn)
    float* p   = (float*)(R + (size_t)MP * FF * 2);      // MP*D*4
    bf16*  obf = (bf16*) (ws + off); off += (size_t)MP * D * 2;

    // attention partials reuse dead buffers: op0 = x2b, op1 = obf, ml in p
    float2* mlbuf = (float2*)p;

    const size_t WQ = (size_t)NL * 3 * D * D;
    const size_t WO = (size_t)NL * D * D;
    const size_t W1E = (size_t)NL * FF * D;
    const size_t W2E = (size_t)NL * D * FF;
    const size_t WALL = WQ + WO + W1E + W2E;
    bool all_w = (off + WALL * 2) <= ws_size;

    bf16 *wq_a = nullptr, *wo_a = nullptr, *w1_a = nullptr, *w2_a = nullptr, *wbuf = nullptr;
    if (all_w) {
        wq_a = (bf16*)(ws + off);
        wo_a = wq_a + WQ;
        w1_a = wo_a + WO;
        w2_a = w1_a + W1E;
        int n4;
        n4 = (int)(WQ / 4);  cvt_k<<<dim3((n4 + 255) / 256), 256, 0, stream>>>(qkv_w, wq_a, n4);
        n4 = (int)(WO / 4);  cvt_k<<<dim3((n4 + 255) / 256), 256, 0, stream>>>(out_w, wo_a, n4);
        n4 = (int)(W1E / 4); cvt_k<<<dim3((n4 + 255) / 256), 256, 0, stream>>>(w1, w1_a, n4);
        n4 = (int)(W2E / 4); cvt_k<<<dim3((n4 + 255) / 256), 256, 0, stream>>>(w2, w2_a, n4);
    } else {
        wbuf = (bf16*)(ws + off); // per-layer rotating buffer
    }

    const int M = B * L;
    {
        long total = (long)B * L * D;
        embed_k<<<dim3((unsigned)((total + 255) / 256)), 256, 0, stream>>>(src, emb, cls_token, x, xb);
    }
    for (int l = 0; l < NL; l++) {
        const float* qb  = qkv_b + (size_t)l * 3 * D;
        const float* obi = out_b + (size_t)l * D;
        const float* re  = rel_emb + (size_t)l * (2 * MAXD + 1) * H;
        const float* g1  = ln1_g + (size_t)l * D;
        const float* be1 = ln1_b + (size_t)l * D;
        const float* B1p = b1 + (size_t)l * FF;
        const float* B2p = b2 + (size_t)l * D;
        const float* g2  = ln2_g + (size_t)l * D;
        const float* be2 = ln2_b + (size_t)l * D;

        const bf16 *wqb, *wob, *w1b, *w2b;
        if (all_w) {
            wqb = wq_a + (size_t)l * 3 * D * D;
            wob = wo_a + (size_t)l * D * D;
            w1b = w1_a + (size_t)l * FF * D;
            w2b = w2_a + (size_t)l * D * FF;
        } else {
            bf16* wp_ = wbuf;
            wqb = wp_;            wp_ += 3 * D * D;
            wob = wp_;            wp_ += D * D;
            w1b = wp_;            wp_ += FF * D;
            w2b = wp_;
            int n4;
            n4 = 3 * D * D / 4; cvt_k<<<dim3((n4 + 255) / 256), 256, 0, stream>>>(qkv_w + (size_t)l * 3 * D * D, (bf16*)wqb, n4);
            n4 = D * D / 4;     cvt_k<<<dim3((n4 + 255) / 256), 256, 0, stream>>>(out_w + (size_t)l * D * D, (bf16*)wob, n4);
            n4 = FF * D / 4;    cvt_k<<<dim3((n4 + 255) / 256), 256, 0, stream>>>(w1 + (size_t)l * FF * D, (bf16*)w1b, n4);
            n4 = D * FF / 4;    cvt_k<<<dim3((n4 + 255) / 256), 256, 0, stream>>>(w2 + (size_t)l * D * FF, (bf16*)w2b, n4);
        }

        mgemm<0, 1, 1, 128><<<dim3(3 * D / 128, MP / 128), 256, 0, stream>>>(xb, wqb, qb, nullptr, qkvb, 3 * D, D, D);
        fattn_k<<<dim3(B * H, 9, 2), 256, 0, stream>>>(qkvb, re, pad, x2b, obf, mlbuf);
        comb_k<<<dim3(M), 256, 0, stream>>>(x2b, obf, mlbuf, obf);
        mgemm<0, 0, 1, 64><<<dim3(D / 128, MP / 64), 256, 0, stream>>>(obf, wob, obi, p, nullptr, D, D, D);
        add_ln_k<<<dim3(M), 256, 0, stream>>>(x, p, g1, be1, x2, x2b);
        mgemm<1, 1, 1, 128><<<dim3(FF / 128, MP / 128), 256, 0, stream>>>(x2b, w1b, B1p, nullptr, hb, FF, D, D);
        mgemm<0, 0, 1, 64><<<dim3(D / 128, MP / 64), 256, 0, stream>>>(hb, w2b, B2p, p, nullptr, D, FF, FF);
        add_ln_k<<<dim3(M), 256, 0, stream>>>(x2, p, g2, be2, x, xb);
    }
    cls_k<<<dim3(B), 256, 0, stream>>>(x, norm_g, norm_b, cls_w, cls_b, out);
}

// Round 19
// 1418.293 us; speedup vs baseline: 1.4050x; 1.0314x over previous
//
#include <hip/hip_runtime.h>
#include <hip/hip_bf16.h>
#include <stdint.h>

#define B 8
#define S 1024
#define L 1025
#define D 512
#define H 8
#define HD 64
#define NL 6
#define FF 2048
#define MAXD 64
#define OUTLEN 8
#define NC 10

#define MP 8320   // 65 * 128, padded M

typedef __bf16 bf16;
typedef __bf16 bf16x8 __attribute__((ext_vector_type(8)));
typedef __bf16 bf16x4 __attribute__((ext_vector_type(4)));
typedef __bf16 bf16x2 __attribute__((ext_vector_type(2)));
typedef float f32x4 __attribute__((ext_vector_type(4)));

__device__ __forceinline__ float fexp2(float x) { return __builtin_amdgcn_exp2f(x); }

// barrier WITHOUT the vmcnt(0) drain
#define LGKM_BARRIER() asm volatile("s_waitcnt lgkmcnt(0)\ns_barrier" ::: "memory")

__device__ __forceinline__ void gld16(const void* g, void* l) {
    __builtin_amdgcn_global_load_lds(
        (const __attribute__((address_space(1))) unsigned int*)g,
        (__attribute__((address_space(3))) unsigned int*)l,
        16, 0, 0);
}

// GELU with A&S 7.1.26 erf (|err| <= 1.5e-7), no libm call
__device__ __forceinline__ float fast_gelu(float v) {
    float x = v * 0.70710678118654752f;
    float ax = fabsf(x);
    float t = 1.f / fmaf(0.3275911f, ax, 1.f);
    float poly = t * (0.254829592f + t * (-0.284496736f + t * (1.421413741f +
                 t * (-1.453152027f + t * 1.061405429f))));
    float e = fexp2(-ax * ax * 1.4426950408889634f);
    float erfv = 1.f - poly * e;
    erfv = copysignf(erfv, x);
    return 0.5f * v * (1.f + erfv);
}

// ---------------- f32 -> bf16 conversion (vectorized) ----------------
__global__ __launch_bounds__(256) void cvt_k(const float* __restrict__ in,
                                             bf16* __restrict__ out, int n4)
{
    int i = blockIdx.x * 256 + threadIdx.x;
    if (i >= n4) return;
    float4 v = reinterpret_cast<const float4*>(in)[i];
    bf16x4 o;
    o[0] = (bf16)v.x; o[1] = (bf16)v.y; o[2] = (bf16)v.z; o[3] = (bf16)v.w;
    reinterpret_cast<bf16x4*>(out)[i] = o;
}

// ---------------- embedding (bf16 out only) ----------------
__global__ void embed_k(const int* __restrict__ src, const float* __restrict__ emb,
                        const float* __restrict__ cls, bf16* __restrict__ xb)
{
    long i = (long)blockIdx.x * blockDim.x + threadIdx.x;
    if (i >= (long)B * L * D) return;
    int d = (int)(i % D);
    long bl = i / D;
    int l = (int)(bl % L);
    int b = (int)(bl / L);
    float v = (l == 0) ? cls[d] : emb[(long)src[b * S + (l - 1)] * D + d];
    xb[i] = (bf16)v;
}

// ---------------- MFMA bf16 GEMM, 2-phase double-buffered LDS (R14) ----------
template<int ACT, int OBF, int BIAS, int RT>
__global__ __launch_bounds__(256) void mgemm(const bf16* __restrict__ A,
                                             const bf16* __restrict__ W,
                                             const float* __restrict__ bias,
                                             float* __restrict__ Cf,
                                             bf16* __restrict__ Cb,
                                             int N, int K, int LDA)
{
    __shared__ bf16 Asl[2][RT * 32];
    __shared__ bf16 Bsl[2][128 * 32];
    int tid = threadIdx.x;
    int m0 = blockIdx.y * RT;
    int n0 = blockIdx.x * 128;
    int lane = tid & 63;
    int w = tid >> 6;
    int wbase = tid & ~63;
    int kb = (lane >> 4) * 8;
    int rsel = lane & 15;
    constexpr int FJ = (RT == 128) ? 4 : 2;
    constexpr int CW = (RT == 128) ? 64 : 32;
    int wr, wc;
    if constexpr (RT == 128) { wr = w >> 1; wc = w & 1; }
    else                     { wr = 0;      wc = w;     }
    f32x4 acc[4][FJ] = {};

    auto stage = [&](int buf, int k0) {
        if constexpr (RT == 128) {
#pragma unroll
            for (int r = 0; r < 2; r++) {
                int s = r * 256 + tid;
                int sb = r * 256 + wbase;
                gld16(A + (size_t)(m0 + (s >> 2)) * LDA + k0 + (s & 3) * 8, &Asl[buf][(size_t)sb * 8]);
                gld16(W + (size_t)(n0 + (s >> 2)) * LDA + k0 + (s & 3) * 8, &Bsl[buf][(size_t)sb * 8]);
            }
        } else {
            gld16(A + (size_t)(m0 + (tid >> 2)) * LDA + k0 + (tid & 3) * 8, &Asl[buf][(size_t)wbase * 8]);
#pragma unroll
            for (int r = 0; r < 2; r++) {
                int s = r * 256 + tid;
                int sb = r * 256 + wbase;
                gld16(W + (size_t)(n0 + (s >> 2)) * LDA + k0 + (s & 3) * 8, &Bsl[buf][(size_t)sb * 8]);
            }
        }
    };

    stage(0, 0);
    __syncthreads();

    for (int k0 = 0; k0 < K; k0 += 32) {
        int cur = (k0 >> 5) & 1;
        if (k0 + 32 < K) stage(cur ^ 1, k0 + 32);
        bf16x8 af[4], bfr[FJ];
#pragma unroll
        for (int fi = 0; fi < 4; fi++)
            af[fi] = *reinterpret_cast<const bf16x8*>(&Asl[cur][(wr * 64 + fi * 16 + rsel) * 32 + kb]);
#pragma unroll
        for (int fj = 0; fj < FJ; fj++)
            bfr[fj] = *reinterpret_cast<const bf16x8*>(&Bsl[cur][(wc * CW + fj * 16 + rsel) * 32 + kb]);
#pragma unroll
        for (int fi = 0; fi < 4; fi++)
#pragma unroll
            for (int fj = 0; fj < FJ; fj++)
                acc[fi][fj] = __builtin_amdgcn_mfma_f32_16x16x32_bf16(af[fi], bfr[fj], acc[fi][fj], 0, 0, 0);
        __syncthreads();
    }
    int rowb = (lane >> 4) * 4;
    int colb = lane & 15;
#pragma unroll
    for (int fi = 0; fi < 4; fi++) {
#pragma unroll
        for (int fj = 0; fj < FJ; fj++) {
            int col = n0 + wc * CW + fj * 16 + colb;
            float bsv = BIAS ? bias[col] : 0.f;
#pragma unroll
            for (int i = 0; i < 4; i++) {
                int row = m0 + wr * 64 + fi * 16 + rowb + i;
                float v = acc[fi][fj][i] + bsv;
                if (ACT) v = fast_gelu(v);
                if (OBF) Cb[(size_t)row * N + col] = (bf16)v;
                else     Cf[(size_t)row * N + col] = v;
            }
        }
    }
}

// ---------------- MFMA flash attention v9: KV-split (2 halves) ---------------
__global__ __launch_bounds__(256) void fattn_k(const bf16* __restrict__ qkv,
                                               const float* __restrict__ rel_emb_l,
                                               const unsigned char* __restrict__ pad,
                                               bf16* __restrict__ op0,
                                               bf16* __restrict__ op1,
                                               float2* __restrict__ mlout)
{
    constexpr int PIT = 72;
    __shared__ bf16 Vt[3][64 * PIT];
    __shared__ bf16 Psh[4][2][16 * PIT];
    __shared__ float bias2s[2 * MAXD + 1];
    __shared__ float colm[2][64];

    const int bh = blockIdx.x;
    const int qt = blockIdx.y;
    const int z = blockIdx.z;
    const int tbeg = z ? 9 : 0;
    const int tend = z ? 17 : 9;
    bf16* opart = z ? op1 : op0;
    const int h = bh & 7, b = bh >> 3;
    const int q0 = qt * 128;
    const int tid = threadIdx.x;
    const int lane = tid & 63;
    const int w = tid >> 6;
    const int ln15 = lane & 15, g4 = lane >> 4;
    const int kb8 = g4 * 8;
    constexpr float LOG2E = 1.4426950408889634f;
    constexpr float C2 = 0.125f * LOG2E;

    const char* base = (const char*)qkv + (size_t)(b * L) * 3072 + (size_t)h * (HD * 2);

    for (int i = tid; i < 2 * MAXD + 1; i += 256) bias2s[i] = rel_emb_l[i * H + h] * LOG2E;
    if (tid < 64) {
        int gk0 = tbeg * 64 + tid;
        int pi = (gk0 > 0 && gk0 <= 1024) ? gk0 - 1 : 0;
        colm[tbeg & 1][tid] = (gk0 > 1024 || (gk0 > 0 && pad[(size_t)b * S + pi])) ? -1e9f : 0.f;
    }

    int qrow[2];
    bf16x8 qa[2][2];
#pragma unroll
    for (int qq = 0; qq < 2; qq++) {
        qrow[qq] = q0 + qq * 64 + w * 16 + ln15;
        qa[qq][0] = *(const bf16x8*)(base + (size_t)qrow[qq] * 3072 + g4 * 16);
        qa[qq][1] = *(const bf16x8*)(base + (size_t)qrow[qq] * 3072 + 64 + g4 * 16);
    }

    const int vr = tid >> 3;
    const int vd0 = (tid & 7) * 8;
    const int vsw = ((vd0 >> 3) & 7) << 3;

    { // prologue: stage V tile tbeg into Vt[0]
        int kv0 = tbeg * 64;
        bf16x8 a = *(const bf16x8*)(base + (size_t)(kv0 + vr) * 3072 + 2048 + vd0 * 2);
        bf16x8 c = *(const bf16x8*)(base + (size_t)(kv0 + vr + 32) * 3072 + 2048 + vd0 * 2);
#pragma unroll
        for (int j = 0; j < 8; j++) {
            Vt[0][(vd0 + j) * PIT + (vr ^ vsw)] = a[j];
            Vt[0][(vd0 + j) * PIT + ((vr + 32) ^ vsw)] = c[j];
        }
    }
    bf16x8 kr[4][2];
#pragma unroll
    for (int fj = 0; fj < 4; fj++) {
        const char* rp = base + (size_t)(tbeg * 64 + fj * 16 + ln15) * 3072 + 1024 + g4 * 16;
        kr[fj][0] = *(const bf16x8*)(rp);
        kr[fj][1] = *(const bf16x8*)(rp + 64);
    }
    LGKM_BARRIER();

    f32x4 oacc[2][4] = {};
    float m_prev[2] = {-1e30f, -1e30f};
    float l_sum[2] = {0.f, 0.f};

    int cur3 = 0;
    for (int t = tbeg; t < tend; t++) {
        const int k0 = t * 64;
        const int k0n = (k0 + 64 > 1024) ? 1024 : (k0 + 64);
        const int curM = t & 1;
        int nxt3 = cur3 + 1; if (nxt3 == 3) nxt3 = 0;

        bf16x8 vA = *(const bf16x8*)(base + (size_t)(k0n + vr) * 3072 + 2048 + vd0 * 2);
        bf16x8 vB = *(const bf16x8*)(base + (size_t)(k0n + vr + 32) * 3072 + 2048 + vd0 * 2);

        f32x4 sacc[2][4] = {};
#pragma unroll
        for (int qq = 0; qq < 2; qq++)
#pragma unroll
            for (int fj = 0; fj < 4; fj++) {
                sacc[qq][fj] = __builtin_amdgcn_mfma_f32_16x16x32_bf16(kr[fj][0], qa[qq][0], sacc[qq][fj], 0, 0, 0);
                sacc[qq][fj] = __builtin_amdgcn_mfma_f32_16x16x32_bf16(kr[fj][1], qa[qq][1], sacc[qq][fj], 0, 0, 0);
            }
#pragma unroll
        for (int fj = 0; fj < 4; fj++) {
            const char* rp = base + (size_t)(k0n + fj * 16 + ln15) * 3072 + 1024 + g4 * 16;
            kr[fj][0] = *(const bf16x8*)(rp);
            kr[fj][1] = *(const bf16x8*)(rp + 64);
        }

        f32x4 cm[4];
#pragma unroll
        for (int fj = 0; fj < 4; fj++)
            cm[fj] = *(const f32x4*)&colm[curM][fj * 16 + g4 * 4];

#pragma unroll
        for (int qq = 0; qq < 2; qq++) {
            float sv[4][4];
            const int relbw = k0 - q0 - qq * 64 - w * 16;
            if (relbw >= MAXD + 15 || relbw <= -MAXD - 63) {
                const float bu = bias2s[relbw > 0 ? 2 * MAXD : 0];
#pragma unroll
                for (int fj = 0; fj < 4; fj++)
#pragma unroll
                    for (int i = 0; i < 4; i++)
                        sv[fj][i] = fmaf(sacc[qq][fj][i], C2, bu + cm[fj][i]);
            } else {
                const int relb = k0 - qrow[qq];
#pragma unroll
                for (int fj = 0; fj < 4; fj++)
#pragma unroll
                    for (int i = 0; i < 4; i++) {
                        int rel = relb + fj * 16 + g4 * 4 + i;
                        rel = rel < -MAXD ? -MAXD : (rel > MAXD ? MAXD : rel);
                        sv[fj][i] = fmaf(sacc[qq][fj][i], C2, bias2s[rel + MAXD] + cm[fj][i]);
                    }
            }

            float mx = sv[0][0];
#pragma unroll
            for (int fj = 0; fj < 4; fj++)
#pragma unroll
                for (int i = 0; i < 4; i++) mx = fmaxf(mx, sv[fj][i]);
            mx = fmaxf(mx, __shfl_xor(mx, 16));
            mx = fmaxf(mx, __shfl_xor(mx, 32));
            const float mnew = fmaxf(m_prev[qq], mx);
            const float corr = fexp2(m_prev[qq] - mnew);
            float rsum = 0.f;
            float pb[4][4];
#pragma unroll
            for (int fj = 0; fj < 4; fj++)
#pragma unroll
                for (int i = 0; i < 4; i++) {
                    float p = fexp2(sv[fj][i] - mnew);
                    pb[fj][i] = p;
                    rsum += p;
                }
            rsum += __shfl_xor(rsum, 16);
            rsum += __shfl_xor(rsum, 32);
            l_sum[qq] = l_sum[qq] * corr + rsum;
            m_prev[qq] = mnew;
#pragma unroll
            for (int fd = 0; fd < 4; fd++) oacc[qq][fd] *= corr;

#pragma unroll
            for (int fj = 0; fj < 4; fj++) {
                union { bf16 hh[4]; unsigned long long u; } pk;
                pk.hh[0] = (bf16)pb[fj][0]; pk.hh[1] = (bf16)pb[fj][1];
                pk.hh[2] = (bf16)pb[fj][2]; pk.hh[3] = (bf16)pb[fj][3];
                *(unsigned long long*)&Psh[w][qq][ln15 * PIT + fj * 16 + g4 * 4] = pk.u;
            }
        }

        // commit next V tile into Vt[nxt3] + next colm
#pragma unroll
        for (int j = 0; j < 8; j++) {
            Vt[nxt3][(vd0 + j) * PIT + (vr ^ vsw)] = vA[j];
            Vt[nxt3][(vd0 + j) * PIT + ((vr + 32) ^ vsw)] = vB[j];
        }
        if (tid < 64) {
            int gk = k0 + 64 + tid;
            int pi = (gk <= 1024) ? gk - 1 : 0;
            colm[curM ^ 1][tid] = (gk > 1024 || pad[(size_t)b * S + pi]) ? -1e9f : 0.f;
        }

        LGKM_BARRIER();   // single barrier per tile

        bf16x8 pa[2][2];
#pragma unroll
        for (int qq = 0; qq < 2; qq++) {
            pa[qq][0] = *(const bf16x8*)&Psh[w][qq][ln15 * PIT + kb8];
            pa[qq][1] = *(const bf16x8*)&Psh[w][qq][ln15 * PIT + 32 + kb8];
        }
#pragma unroll
        for (int fd = 0; fd < 4; fd++) {
            const int d = fd * 16 + ln15;
            const int vx = ((d >> 3) & 7) << 3;
            bf16x8 af0 = *(const bf16x8*)&Vt[cur3][d * PIT + (kb8 ^ vx)];
            bf16x8 af1 = *(const bf16x8*)&Vt[cur3][d * PIT + ((32 + kb8) ^ vx)];
            oacc[0][fd] = __builtin_amdgcn_mfma_f32_16x16x32_bf16(af0, pa[0][0], oacc[0][fd], 0, 0, 0);
            oacc[0][fd] = __builtin_amdgcn_mfma_f32_16x16x32_bf16(af1, pa[0][1], oacc[0][fd], 0, 0, 0);
            oacc[1][fd] = __builtin_amdgcn_mfma_f32_16x16x32_bf16(af0, pa[1][0], oacc[1][fd], 0, 0, 0);
            oacc[1][fd] = __builtin_amdgcn_mfma_f32_16x16x32_bf16(af1, pa[1][1], oacc[1][fd], 0, 0, 0);
        }
        cur3 = nxt3;
    }

    // epilogue: normalized partial O + (m, l) per q-row
#pragma unroll
    for (int qq = 0; qq < 2; qq++) {
        if (qrow[qq] < L) {
            const float inv = 1.f / l_sum[qq];
            bf16* op = opart + (size_t)(b * L + qrow[qq]) * D + h * HD + g4 * 4;
#pragma unroll
            for (int fd = 0; fd < 4; fd++) {
                bf16x4 r;
#pragma unroll
                for (int i = 0; i < 4; i++) r[i] = (bf16)(oacc[qq][fd][i] * inv);
                *(bf16x4*)(op + fd * 16) = r;
            }
            if (g4 == 0)
                mlout[(size_t)(z * 64 + b * 8 + h) * 1025 + qrow[qq]] =
                    make_float2(m_prev[qq], l_sum[qq]);
        }
    }
}

// ---------------- combine the 2 KV-half partials -> obf ----------------
__global__ __launch_bounds__(256) void comb_k(const bf16* __restrict__ op0,
                                              const bf16* __restrict__ op1,
                                              const float2* __restrict__ ml,
                                              bf16* __restrict__ ob)
{
    int row = blockIdx.x;             // b*L + q
    int b = row / L, q = row - b * L;
    int tid = threadIdx.x;
    int d = tid & 63;
    int h0 = tid >> 6;
#pragma unroll
    for (int hh = 0; hh < 2; hh++) {
        int h = h0 + hh * 4;
        float2 a = ml[(size_t)(b * 8 + h) * 1025 + q];
        float2 c = ml[(size_t)(64 + b * 8 + h) * 1025 + q];
        float m = fmaxf(a.x, c.x);
        float s1 = a.y * fexp2(a.x - m);
        float s2 = c.y * fexp2(c.x - m);
        float inv = 1.f / (s1 + s2);
        size_t idx = (size_t)row * D + h * HD + d;
        float o = (s1 * (float)op0[idx] + s2 * (float)op1[idx]) * inv;
        ob[idx] = (bf16)o;
    }
}

// ---------------- out = LayerNorm(xin + rin), all-bf16 I/O ----------------
__global__ __launch_bounds__(256) void add_ln_k(const bf16* __restrict__ xin,
                                                const bf16* __restrict__ rin,
                                                const float* __restrict__ g,
                                                const float* __restrict__ bb,
                                                bf16* __restrict__ outb)
{
    int row = blockIdx.x;
    __shared__ float red[8];
    int tid = threadIdx.x;
    bf16x2 a = reinterpret_cast<const bf16x2*>(xin + (size_t)row * D)[tid];
    bf16x2 r = reinterpret_cast<const bf16x2*>(rin + (size_t)row * D)[tid];
    float v0 = (float)a[0] + (float)r[0];
    float v1 = (float)a[1] + (float)r[1];
    float s = v0 + v1;
    for (int off = 32; off; off >>= 1) s += __shfl_down(s, off, 64);
    int lane = tid & 63, wid = tid >> 6;
    if (lane == 0) red[wid] = s;
    __syncthreads();
    if (tid == 0) red[0] = red[0] + red[1] + red[2] + red[3];
    __syncthreads();
    float mean = red[0] * (1.f / D);
    float d0 = v0 - mean, d1 = v1 - mean;
    float sq = d0 * d0 + d1 * d1;
    for (int off = 32; off; off >>= 1) sq += __shfl_down(sq, off, 64);
    if (lane == 0) red[4 + wid] = sq;
    __syncthreads();
    if (tid == 0) red[4] = red[4] + red[5] + red[6] + red[7];
    __syncthreads();
    float rs = rsqrtf(red[4] * (1.f / D) + 1e-5f);
    float r0 = d0 * rs * g[2 * tid] + bb[2 * tid];
    float r1 = d1 * rs * g[2 * tid + 1] + bb[2 * tid + 1];
    bf16x2 o;
    o[0] = (bf16)r0; o[1] = (bf16)r1;
    reinterpret_cast<bf16x2*>(outb + (size_t)row * D)[tid] = o;
}

// ---------------- final LN (row 0 only, bf16 in) + classifier ----------------
__global__ __launch_bounds__(256) void cls_k(const bf16* __restrict__ x,
                                             const float* __restrict__ ng,
                                             const float* __restrict__ nb,
                                             const float* __restrict__ cw,
                                             const float* __restrict__ cb,
                                             float* __restrict__ out)
{
    int b = blockIdx.x;
    __shared__ float xn[D];
    __shared__ float red[8];
    int tid = threadIdx.x;
    const bf16* xp = x + (size_t)(b * L) * D;
    float v0 = (float)xp[tid], v1 = (float)xp[tid + 256];
    float s = v0 + v1;
    for (int off = 32; off; off >>= 1) s += __shfl_down(s, off, 64);
    int lane = tid & 63, wid = tid >> 6;
    if (lane == 0) red[wid] = s;
    __syncthreads();
    if (tid == 0) red[0] = red[0] + red[1] + red[2] + red[3];
    __syncthreads();
    float mean = red[0] * (1.f / D);
    float d0 = v0 - mean, d1 = v1 - mean;
    float sq = d0 * d0 + d1 * d1;
    for (int off = 32; off; off >>= 1) sq += __shfl_down(sq, off, 64);
    if (lane == 0) red[4 + wid] = sq;
    __syncthreads();
    if (tid == 0) red[4] = red[4] + red[5] + red[6] + red[7];
    __syncthreads();
    float rs = rsqrtf(red[4] * (1.f / D) + 1e-5f);
    xn[tid] = d0 * rs * ng[tid] + nb[tid];
    xn[tid + 256] = d1 * rs * ng[tid + 256] + nb[tid + 256];
    __syncthreads();
    for (int o = tid; o < OUTLEN * NC; o += 256) {
        float acc = cb[o];
        const float* wp = cw + (size_t)o * D;
        for (int d = 0; d < D; d++) acc += xn[d] * wp[d];
        out[b * OUTLEN * NC + o] = acc;
    }
}

extern "C" void kernel_launch(void* const* d_in, const int* in_sizes, int n_in,
                              void* d_out, int out_size, void* d_ws, size_t ws_size,
                              hipStream_t stream) {
    const int* src = (const int*)d_in[0];
    const unsigned char* pad = (const unsigned char*)d_in[1];
    const float* emb = (const float*)d_in[2];
    const float* cls_token = (const float*)d_in[3];
    const float* qkv_w = (const float*)d_in[4];
    const float* qkv_b = (const float*)d_in[5];
    const float* out_w = (const float*)d_in[6];
    const float* out_b = (const float*)d_in[7];
    const float* rel_emb = (const float*)d_in[8];
    const float* ln1_g = (const float*)d_in[9];
    const float* ln1_b = (const float*)d_in[10];
    const float* w1 = (const float*)d_in[11];
    const float* b1 = (const float*)d_in[12];
    const float* w2 = (const float*)d_in[13];
    const float* b2 = (const float*)d_in[14];
    const float* ln2_g = (const float*)d_in[15];
    const float* ln2_b = (const float*)d_in[16];
    const float* norm_g = (const float*)d_in[17];
    const float* norm_b = (const float*)d_in[18];
    const float* cls_w = (const float*)d_in[19];
    const float* cls_b = (const float*)d_in[20];
    float* out = (float*)d_out;

    char* ws = (char*)d_ws;
    size_t off = 0;
    bf16*  xb  = (bf16*) (ws + off); off += (size_t)MP * D * 2;   // residual x (bf16)
    bf16*  x2b = (bf16*) (ws + off); off += (size_t)MP * D * 2;   // x2 / attn partial 0
    char*  R   = ws + off;           off += (size_t)MP * 3 * D * 4; // qkvb | (hb + pb + ml)
    bf16*  qkvb = (bf16*)R;                                       // MP*3D*2 = 25.6 MB
    bf16*  hb  = (bf16*)R;                                        // MP*FF*2 = 34.1 MB (after attn)
    bf16*  pb  = (bf16*)(R + (size_t)MP * FF * 2);                // MP*D*2  (disjoint from qkvb)
    float2* mlbuf = (float2*)(R + (size_t)MP * FF * 2 + (size_t)MP * D * 2);  // 1.05 MB
    bf16*  obf = (bf16*) (ws + off); off += (size_t)MP * D * 2;   // attn out / partial 1

    const size_t WQ = (size_t)NL * 3 * D * D;
    const size_t WO = (size_t)NL * D * D;
    const size_t W1E = (size_t)NL * FF * D;
    const size_t W2E = (size_t)NL * D * FF;
    const size_t WALL = WQ + WO + W1E + W2E;
    bool all_w = (off + WALL * 2) <= ws_size;

    bf16 *wq_a = nullptr, *wo_a = nullptr, *w1_a = nullptr, *w2_a = nullptr, *wbuf = nullptr;
    if (all_w) {
        wq_a = (bf16*)(ws + off);
        wo_a = wq_a + WQ;
        w1_a = wo_a + WO;
        w2_a = w1_a + W1E;
        int n4;
        n4 = (int)(WQ / 4);  cvt_k<<<dim3((n4 + 255) / 256), 256, 0, stream>>>(qkv_w, wq_a, n4);
        n4 = (int)(WO / 4);  cvt_k<<<dim3((n4 + 255) / 256), 256, 0, stream>>>(out_w, wo_a, n4);
        n4 = (int)(W1E / 4); cvt_k<<<dim3((n4 + 255) / 256), 256, 0, stream>>>(w1, w1_a, n4);
        n4 = (int)(W2E / 4); cvt_k<<<dim3((n4 + 255) / 256), 256, 0, stream>>>(w2, w2_a, n4);
    } else {
        wbuf = (bf16*)(ws + off); // per-layer rotating buffer
    }

    const int M = B * L;
    {
        long total = (long)B * L * D;
        embed_k<<<dim3((unsigned)((total + 255) / 256)), 256, 0, stream>>>(src, emb, cls_token, xb);
    }
    for (int l = 0; l < NL; l++) {
        const float* qb  = qkv_b + (size_t)l * 3 * D;
        const float* obi = out_b + (size_t)l * D;
        const float* re  = rel_emb + (size_t)l * (2 * MAXD + 1) * H;
        const float* g1  = ln1_g + (size_t)l * D;
        const float* be1 = ln1_b + (size_t)l * D;
        const float* B1p = b1 + (size_t)l * FF;
        const float* B2p = b2 + (size_t)l * D;
        const float* g2  = ln2_g + (size_t)l * D;
        const float* be2 = ln2_b + (size_t)l * D;

        const bf16 *wqb, *wob, *w1b, *w2b;
        if (all_w) {
            wqb = wq_a + (size_t)l * 3 * D * D;
            wob = wo_a + (size_t)l * D * D;
            w1b = w1_a + (size_t)l * FF * D;
            w2b = w2_a + (size_t)l * D * FF;
        } else {
            bf16* wp_ = wbuf;
            wqb = wp_;            wp_ += 3 * D * D;
            wob = wp_;            wp_ += D * D;
            w1b = wp_;            wp_ += FF * D;
            w2b = wp_;
            int n4;
            n4 = 3 * D * D / 4; cvt_k<<<dim3((n4 + 255) / 256), 256, 0, stream>>>(qkv_w + (size_t)l * 3 * D * D, (bf16*)wqb, n4);
            n4 = D * D / 4;     cvt_k<<<dim3((n4 + 255) / 256), 256, 0, stream>>>(out_w + (size_t)l * D * D, (bf16*)wob, n4);
            n4 = FF * D / 4;    cvt_k<<<dim3((n4 + 255) / 256), 256, 0, stream>>>(w1 + (size_t)l * FF * D, (bf16*)w1b, n4);
            n4 = D * FF / 4;    cvt_k<<<dim3((n4 + 255) / 256), 256, 0, stream>>>(w2 + (size_t)l * D * FF, (bf16*)w2b, n4);
        }

        mgemm<0, 1, 1, 128><<<dim3(3 * D / 128, MP / 128), 256, 0, stream>>>(xb, wqb, qb, nullptr, qkvb, 3 * D, D, D);
        fattn_k<<<dim3(B * H, 9, 2), 256, 0, stream>>>(qkvb, re, pad, x2b, obf, mlbuf);
        comb_k<<<dim3(M), 256, 0, stream>>>(x2b, obf, mlbuf, obf);
        mgemm<0, 1, 1, 64><<<dim3(D / 128, MP / 64), 256, 0, stream>>>(obf, wob, obi, nullptr, pb, D, D, D);
        add_ln_k<<<dim3(M), 256, 0, stream>>>(xb, pb, g1, be1, x2b);
        mgemm<1, 1, 1, 128><<<dim3(FF / 128, MP / 128), 256, 0, stream>>>(x2b, w1b, B1p, nullptr, hb, FF, D, D);
        mgemm<0, 1, 1, 64><<<dim3(D / 128, MP / 64), 256, 0, stream>>>(hb, w2b, B2p, nullptr, pb, D, FF, FF);
        add_ln_k<<<dim3(M), 256, 0, stream>>>(x2b, pb, g2, be2, xb);
    }
    cls_k<<<dim3(B), 256, 0, stream>>>(xb, norm_g, norm_b, cls_w, cls_b, out);
}